// Round 11
// baseline (1382.263 us; speedup 1.0000x reference)
//
#include <hip/hip_runtime.h>
#include <math.h>

#define NN 50000
#define NE 600000
#define ECAP 230000  // capacity for filtered edges (actual ~175K)
#define DD 128
#define D3 384
#define NB_ 20
#define HH 64
#define NG_ 512
#define LSZ 180224   // shorts per layer of transposed-bf16 weights

typedef short v8s __attribute__((ext_vector_type(8)));
typedef short v4sh __attribute__((ext_vector_type(4)));
typedef float v4f __attribute__((ext_vector_type(4)));

__device__ __forceinline__ float silu_f(float z) { return z / (1.0f + expf(-z)); }

__device__ __forceinline__ short f2bf(float f) {
  unsigned u = __float_as_uint(f);
  u += 0x7FFF + ((u >> 16) & 1);          // RNE
  return (short)(u >> 16);
}
__device__ __forceinline__ float bf2f(short s) {
  return __uint_as_float(((unsigned)(unsigned short)s) << 16);
}
__device__ __forceinline__ void split2(float x, short& h, short& l) {
  h = f2bf(x);
  l = f2bf(x - bf2f(h));
}
// split a float4 and store hi/lo as short4 (8B LDS stores)
__device__ __forceinline__ void split_store4(float4 f, short* hp, short* lp) {
  short h0,l0,h1,l1,h2,l2,h3,l3;
  split2(f.x,h0,l0); split2(f.y,h1,l1); split2(f.z,h2,l2); split2(f.w,h3,l3);
  v4sh hv = {h0,h1,h2,h3}, lv = {l0,l1,l2,l3};
  *(v4sh*)hp = hv; *(v4sh*)lp = lv;
}
// 3-term Markidis split: acc += ah@bh + al@bh + ah@bl   (proven: absmax 4.3e9)
#define MFMA3(acc, ah, al, bh, bl) \
  acc = __builtin_amdgcn_mfma_f32_16x16x32_bf16(ah, bh, acc, 0, 0, 0); \
  acc = __builtin_amdgcn_mfma_f32_16x16x32_bf16(al, bh, acc, 0, 0, 0); \
  acc = __builtin_amdgcn_mfma_f32_16x16x32_bf16(ah, bl, acc, 0, 0, 0);

// ---------------- utility ----------------
__global__ void zero_f_kernel(float* __restrict__ p, long n) {
  long i = (long)blockIdx.x * blockDim.x + threadIdx.x;
  long s = (long)gridDim.x * blockDim.x;
  for (; i < n; i += s) p[i] = 0.0f;
}

__global__ void zero_i_kernel(int* __restrict__ p, long n) {
  long i = (long)blockIdx.x * blockDim.x + threadIdx.x;
  long s = (long)gridDim.x * blockDim.x;
  for (; i < n; i += s) p[i] = 0;
}

__global__ void init_x_kernel(const int* __restrict__ at_no, const float* __restrict__ emb,
                              float* __restrict__ x) {
  int i = blockIdx.x * blockDim.x + threadIdx.x;
  if (i >= NN * DD) return;
  x[i] = emb[at_no[i >> 7] * DD + (i & 127)];
}

// ---------------- weight prep: fp32 [K][N] -> transposed bf16 hi/lo [N][K] ----------------
__global__ void prep_w_kernel(const float* __restrict__ Wm1, const float* __restrict__ Wm2,
                              const float* __restrict__ U, const float* __restrict__ V,
                              const float* __restrict__ Wu1, const float* __restrict__ Wu2,
                              short* __restrict__ hi, short* __restrict__ lo) {
  int idx = blockIdx.x * 256 + threadIdx.x;
  if (idx >= 3 * LSZ) return;
  int l = idx / LSZ, r = idx % LSZ;
  const float* src; int K, N, nk;
  if (r < 16384)       { src = Wm1 + (size_t)l*16384; K = 128; N = 128; nk = r; }
  else if (r < 65536)  { src = Wm2 + (size_t)l*49152; K = 128; N = 384; nk = r - 16384; }
  else if (r < 81920)  { src = U   + (size_t)l*16384; K = 128; N = 128; nk = r - 65536; }
  else if (r < 98304)  { src = V   + (size_t)l*16384; K = 128; N = 128; nk = r - 81920; }
  else if (r < 131072) { src = Wu1 + (size_t)l*32768; K = 256; N = 128; nk = r - 98304; }
  else                 { src = Wu2 + (size_t)l*49152; K = 128; N = 384; nk = r - 131072; }
  int n = nk / K, k = nk - n * K;
  float xx = src[(size_t)k * N + n];
  short h = f2bf(xx);
  hi[idx] = h;
  lo[idx] = f2bf(xx - bf2f(h));
}

// Wo1 transpose: [DD][HH] -> Wo1T[HH][DD] so the fused head reads contiguous float4
__global__ void prep_wo_kernel(const float* __restrict__ Wo1, float* __restrict__ Wo1T) {
  int idx = blockIdx.x * 256 + threadIdx.x;
  if (idx >= DD * HH) return;
  int h = idx >> 7, d = idx & 127;
  Wo1T[h * DD + d] = Wo1[d * HH + h];
}

// ---------------- CSR build (dst-sorted), filtering dist>=CUTOFF edges ----------------
__global__ void hist_kernel(const int* __restrict__ ei, const float* __restrict__ pos,
                            int* __restrict__ counts) {
  int e = blockIdx.x * blockDim.x + threadIdx.x;
  if (e >= NE) return;
  int s = ei[e], d = ei[NE + e];
  float dx = pos[3*d]   - pos[3*s];
  float dy = pos[3*d+1] - pos[3*s+1];
  float dz = pos[3*d+2] - pos[3*s+2];
  float d2 = dx*dx + dy*dy + dz*dz + 1e-12f;
  if (d2 < 25.0f) atomicAdd(&counts[d], 1);
}

__global__ void scan_kernel(const int* __restrict__ counts, int* __restrict__ indptr, int n) {
  __shared__ int sm[1024];
  __shared__ int carry_s;
  if (threadIdx.x == 0) carry_s = 0;
  __syncthreads();
  for (int start = 0; start < n; start += 1024) {
    int i = start + (int)threadIdx.x;
    int val = (i < n) ? counts[i] : 0;
    sm[threadIdx.x] = val;
    __syncthreads();
    for (int off = 1; off < 1024; off <<= 1) {
      int t = (threadIdx.x >= (unsigned)off) ? sm[threadIdx.x - off] : 0;
      __syncthreads();
      sm[threadIdx.x] += t;
      __syncthreads();
    }
    int c = carry_s;
    if (i < n) indptr[i] = c + sm[threadIdx.x] - val;
    __syncthreads();
    if (threadIdx.x == 0) carry_s = c + sm[1023];
    __syncthreads();
  }
  if (threadIdx.x == 0) indptr[n] = carry_s;
}

__global__ void fill_kernel(const int* __restrict__ ei, const float* __restrict__ pos,
                            const int* __restrict__ indptr, int* __restrict__ cursor,
                            int* __restrict__ srcs, float4* __restrict__ eg1,
                            float4* __restrict__ eg2) {
  int e = blockIdx.x * blockDim.x + threadIdx.x;
  if (e >= NE) return;
  int s = ei[e], d = ei[NE + e];
  float dx = pos[3*d]   - pos[3*s];
  float dy = pos[3*d+1] - pos[3*s+1];
  float dz = pos[3*d+2] - pos[3*s+2];
  float d2 = dx*dx + dy*dy + dz*dz + 1e-12f;
  if (d2 < 25.0f) {
    int p = atomicAdd(&cursor[d], 1);
    int slot = indptr[d] + p;
    float dist = sqrtf(d2);
    float inv = 1.0f / dist;
    float wang = 0.62831853071795864769f * dist;   // pi*dist/CUTOFF
    float s1 = __sinf(wang), c1 = __cosf(wang);
    float fc = 0.5f * (c1 + 1.0f);
    srcs[slot] = s;
    eg1[slot] = make_float4(s1, c1, fc, fc * inv);
    eg2[slot] = make_float4(dx * inv, dy * inv, dz * inv, 0.0f);
  }
}

// ---------------- fused node MLP: phi = silu(x@Wm1+b1)@Wm2+b2, tri-slice out ----------------
// Row-local chain; t2 never leaves LDS. 512 thr / 8 waves, 32 rows/block.
__global__ void __launch_bounds__(512) mlp_phi_kernel(
    const float* __restrict__ x,
    const short* __restrict__ W1h, const short* __restrict__ W1l, const float* __restrict__ b1,
    const short* __restrict__ W2h, const short* __restrict__ W2l, const float* __restrict__ b2,
    float* __restrict__ C0, float* __restrict__ C1, float* __restrict__ C2, int M) {
  __shared__ short sm[4 * 32 * 136];   // XH | XL | TH | TL
  #define XH_(r,c) sm[(r)*136 + (c)]
  #define XL_(r,c) sm[4352 + (r)*136 + (c)]
  #define TH_(r,c) sm[8704 + (r)*136 + (c)]
  #define TL_(r,c) sm[13056 + (r)*136 + (c)]
  int tid = threadIdx.x;
  long r0 = (long)blockIdx.x * 32;
  #pragma unroll
  for (int i = 0; i < 2; i++) {
    int lin = i*512 + tid;
    int r = lin >> 5, c4 = lin & 31;
    long row = r0 + r; if (row >= M) row = M - 1;
    float4 f = *(const float4*)(x + row*128 + c4*4);
    split_store4(f, &XH_(r, c4*4), &XL_(r, c4*4));
  }
  __syncthreads();
  int lane = tid & 63, wv = tid >> 6;   // wv 0..7
  int l15 = lane & 15, q = lane >> 4;
  // GEMM1: t2 = silu(x@Wm1 + b1); wave w owns cols w*16+l15
  {
    int n = wv*16 + l15;
    v4f acc[2] = {};
    #pragma unroll
    for (int s = 0; s < 4; s++) {
      v8s bh = *(const v8s*)(W1h + (long)n*128 + s*32 + q*8);
      v8s bl = *(const v8s*)(W1l + (long)n*128 + s*32 + q*8);
      #pragma unroll
      for (int mt = 0; mt < 2; mt++) {
        v8s ah = *(const v8s*)&XH_(mt*16 + l15, s*32 + q*8);
        v8s al = *(const v8s*)&XL_(mt*16 + l15, s*32 + q*8);
        MFMA3(acc[mt], ah, al, bh, bl);
      }
    }
    float bb = b1[n];
    #pragma unroll
    for (int mt = 0; mt < 2; mt++)
      #pragma unroll
      for (int i = 0; i < 4; i++) {
        short h, l;
        split2(silu_f(acc[mt][i] + bb), h, l);
        TH_(mt*16 + q*4 + i, n) = h;
        TL_(mt*16 + q*4 + i, n) = l;
      }
  }
  __syncthreads();
  // GEMM2: phi = t2@Wm2 + b2 (384 cols; wave w -> n-tiles w*3..w*3+2)
  v4f acc[2][3] = {};
  #pragma unroll
  for (int s = 0; s < 4; s++) {
    v8s ah[2], al[2];
    #pragma unroll
    for (int mt = 0; mt < 2; mt++) {
      ah[mt] = *(const v8s*)&TH_(mt*16 + l15, s*32 + q*8);
      al[mt] = *(const v8s*)&TL_(mt*16 + l15, s*32 + q*8);
    }
    #pragma unroll
    for (int j = 0; j < 3; j++) {
      int n = (wv*3 + j)*16 + l15;
      v8s bh = *(const v8s*)(W2h + (long)n*128 + s*32 + q*8);
      v8s bl = *(const v8s*)(W2l + (long)n*128 + s*32 + q*8);
      #pragma unroll
      for (int mt = 0; mt < 2; mt++) { MFMA3(acc[mt][j], ah[mt], al[mt], bh, bl); }
    }
  }
  #pragma unroll
  for (int j = 0; j < 3; j++) {
    int n = (wv*3 + j)*16 + l15;
    int sl = n >> 7, col = n & 127;
    float* C = (sl == 0) ? C0 : (sl == 1) ? C1 : C2;
    float bb = b2[n];
    #pragma unroll
    for (int mt = 0; mt < 2; mt++)
      #pragma unroll
      for (int i = 0; i < 4; i++) {
        long row = r0 + mt*16 + q*4 + i;
        if (row < M) C[row*128 + col] = acc[mt][j][i] + bb;
      }
  }
  #undef XH_
  #undef XL_
  #undef TH_
  #undef TL_
}

// ---------------- FUSED message pass + Uv/Vv/Vn/s + a-MLP + update (muva, R24) ----------------
// R24 = R23 + two exact fixes:
//  - first==1 (layer 0): v is identically zero -> skip the 3 vA gather streams in the
//    sweep (half the gather bytes), zero the v-base reads, and the launcher drops the
//    77MB v zero-fill.
//  - fused head (last==1) vectorized: Wo1 pre-transposed to Wo1T[64][128] so the head
//    does float4 LDS + contiguous float4 weight reads (R23's scalar version issued
//    384 scalar loads/thread -> +90us). Same sequential d-order: bit-identical.
__global__ void __launch_bounds__(512, 3) muva_kernel(
    const float* __restrict__ phi0, const float* __restrict__ phi1,
    const float* __restrict__ phi2, const float* __restrict__ vA,
    float* __restrict__ vB, float* __restrict__ x,
    const int* __restrict__ srcs, const float4* __restrict__ eg1,
    const float4* __restrict__ eg2, const int* __restrict__ indptr,
    const float* __restrict__ Wf_l, const float* __restrict__ bf_l,
    const short* __restrict__ Uth, const short* __restrict__ Utl,
    const short* __restrict__ Vth, const short* __restrict__ Vtl,
    const short* __restrict__ W1h, const short* __restrict__ W1l, const float* __restrict__ b1,
    const short* __restrict__ W2h, const short* __restrict__ W2l, const float* __restrict__ b2,
    const float* __restrict__ Wo1T, const float* __restrict__ bo1,
    const float* __restrict__ Wo2, const float* __restrict__ bo2,
    const int* __restrict__ batch, float* __restrict__ out, int last, int first) {
  __shared__ float smem[8896];   // 35584 B
  // region A floats [0,6720): VN [48][140] fp32 deltas during sweep,
  //   then converted IN PLACE to shorts: VNH[48][136] @0 | VNL[48][136] @6528
  //   then overlaid by CATH[16][264] @0 | CATL @4224 | T2H[16][136] @8448 | T2L @10624
  // region B floats [6720,8896): XN [16][136] fp32 (delta then full; intact until epilogue;
  //   on last layer holds FINAL x rows for the fused output head)
  short* sms = (short*)smem;
  #define VN(r,c)   smem[(r)*140 + (c)]
  #define XN(r,c)   smem[6720 + (r)*136 + (c)]
  #define VNH(r,c)  sms[(r)*136 + (c)]
  #define VNL(r,c)  sms[6528 + (r)*136 + (c)]
  #define CATH(r,c) sms[(r)*264 + (c)]
  #define CATL(r,c) sms[4224 + (r)*264 + (c)]
  #define T2H(r,c)  sms[8448 + (r)*136 + (c)]
  #define T2L(r,c)  sms[10624 + (r)*136 + (c)]
  const long NND = (long)NN*DD;
  int tid = threadIdx.x;
  long nb = (long)blockIdx.x * 16;
  // ---- phase E: edge sweep. 4 groups x 128 d-lanes; group g handles nodes 4g..4g+3 ----
  {
    int gs = __builtin_amdgcn_readfirstlane((int)(tid >> 7));   // wave-uniform group id
    int d  = tid & 127;
    float wf0[NB_], wf1[NB_], wf2[NB_];
    #pragma unroll
    for (int k = 0; k < NB_; k++) {
      wf0[k] = Wf_l[k*D3 + d];
      wf1[k] = Wf_l[k*D3 + DD + d];
      wf2[k] = Wf_l[k*D3 + 2*DD + d];
    }
    // pin: make each wf value an asm output -> not rematerializable (R18 behavior kept)
    #pragma unroll
    for (int k = 0; k < NB_; k++) {
      asm volatile("" : "+v"(wf0[k]), "+v"(wf1[k]), "+v"(wf2[k]));
    }
    float bf0 = bf_l[d], bf1 = bf_l[DD + d], bf2 = bf_l[2*DD + d];
    long n0g = nb + 4*gs;
    int b0  = __builtin_amdgcn_readfirstlane(indptr[n0g]);
    int b1_ = __builtin_amdgcn_readfirstlane(indptr[n0g+1]);
    int b2_ = __builtin_amdgcn_readfirstlane(indptr[n0g+2]);
    int b3_ = __builtin_amdgcn_readfirstlane(indptr[n0g+3]);
    int b4_ = __builtin_amdgcn_readfirstlane(indptr[n0g+4]);
    // pipeline state: slot A/B = {per-lane gathers, uniform geometry}; src ring 4 ahead
    int sA = 0, sB = 0;
    float p0A=0,p1A=0,p2A=0,w0A=0,w1A=0,w2A=0;
    float p0B=0,p1B=0,p2B=0,w0B=0,w1B=0,w2B=0;
    float4 g1A={}, g2A={}, g1B={}, g2B={};
    if (b0 < b4_) {
      int s0 = srcs[b0];
      long bb = (long)s0*DD + d;
      p0A = phi0[bb]; p1A = phi1[bb]; p2A = phi2[bb];
      if (!first) { w0A = vA[bb]; w1A = vA[NND+bb]; w2A = vA[2*NND+bb]; }
      g1A = eg1[b0]; g2A = eg2[b0];
    }
    if (b0 + 1 < b4_) {
      int s1v = srcs[b0+1];
      long bb = (long)s1v*DD + d;
      p0B = phi0[bb]; p1B = phi1[bb]; p2B = phi2[bb];
      if (!first) { w0B = vA[bb]; w1B = vA[NND+bb]; w2B = vA[2*NND+bb]; }
      g1B = eg1[b0+1]; g2B = eg2[b0+1];
    }
    if (b0 + 2 < b4_) sA = srcs[b0+2];
    if (b0 + 3 < b4_) sB = srcs[b0+3];
    float xacc=0.f, a0=0.f, a1=0.f, a2=0.f;
    int e = b0, cur = 0, nxt = b1_;
    // body: flush-check -> compute slot -> refill same slot for e+2 (no moves) -> src e+4
#define SW_BODY(P0,P1,P2,W0,W1,W2, G1, G2, SS) \
    { while (e >= nxt) { int nr = 4*gs + cur; \
        XN(nr, d) = xacc; VN(nr, d) = a0; VN(16+nr, d) = a1; VN(32+nr, d) = a2; \
        xacc = 0.f; a0 = 0.f; a1 = 0.f; a2 = 0.f; \
        cur++; nxt = (cur == 1) ? b2_ : (cur == 2) ? b3_ : b4_; } \
      float c2 = 2.0f * G1.y; \
      float rkm1 = 0.f, rk = G1.x, dot0 = 0.f, dot1 = 0.f, dot2 = 0.f; \
      _Pragma("unroll") \
      for (int k = 0; k < NB_; k++) { \
        dot0 = fmaf(rk, wf0[k], dot0); \
        dot1 = fmaf(rk, wf1[k], dot1); \
        dot2 = fmaf(rk, wf2[k], dot2); \
        float rn = fmaf(c2, rk, -rkm1); \
        rkm1 = rk; rk = rn; } \
      xacc = fmaf(P0, bf0*G1.z + G1.w*dot0, xacc); \
      float m1 = P1 * (bf1*G1.z + G1.w*dot1); \
      float m2 = P2 * (bf2*G1.z + G1.w*dot2); \
      a0 = fmaf(m1, G2.x, fmaf(m2, W0, a0)); \
      a1 = fmaf(m1, G2.y, fmaf(m2, W1, a1)); \
      a2 = fmaf(m1, G2.z, fmaf(m2, W2, a2)); \
      if (e + 2 < b4_) { \
        long bb = (long)SS*DD + d; \
        P0 = phi0[bb]; P1 = phi1[bb]; P2 = phi2[bb]; \
        if (!first) { W0 = vA[bb]; W1 = vA[NND+bb]; W2 = vA[2*NND+bb]; } \
        G1 = eg1[e+2]; G2 = eg2[e+2]; } \
      if (e + 4 < b4_) SS = srcs[e+4]; \
      ++e; }
    while (e < b4_) {
      SW_BODY(p0A,p1A,p2A,w0A,w1A,w2A, g1A, g2A, sA)
      if (e >= b4_) break;
      SW_BODY(p0B,p1B,p2B,w0B,w1B,w2B, g1B, g2B, sB)
    }
#undef SW_BODY
    while (cur < 4) {
      int nr = 4*gs + cur;
      XN(nr, d) = xacc; VN(nr, d) = a0; VN(16+nr, d) = a1; VN(32+nr, d) = a2;
      xacc = 0.f; a0 = 0.f; a1 = 0.f; a2 = 0.f;
      cur++;
    }
  }
  // ---- issue base-row loads BEFORE the barrier (overlap with sweep stragglers) ----
  int lane = tid & 63, wv = tid >> 6;   // wv 0..7
  int l15 = lane & 15, q = lane >> 4;
  int dc = wv*16 + l15;                 // this wave's column slice
  float4 vb4[3]; float4 xb4;
  {
    int ch = tid * 3;                   // 1536 float4-chunks: 48 rows x 32
    #pragma unroll
    for (int j = 0; j < 3; j++) {
      if (!first) {
        int r = (ch + j) >> 5, c4 = (ch + j) & 31;
        vb4[j] = *(const float4*)(vA + (long)(r >> 4)*NND + (nb + (r & 15))*DD + c4*4);
      } else {
        vb4[j] = make_float4(0.f, 0.f, 0.f, 0.f);
      }
    }
    int r = tid >> 5, c4 = tid & 31;
    xb4 = *(const float4*)(x + (nb + r)*DD + c4*4);
  }
  float vbold[4][3];
  #pragma unroll
  for (int i = 0; i < 4; i++)
    #pragma unroll
    for (int c = 0; c < 3; c++)
      vbold[i][c] = first ? 0.f : vA[(long)c*NND + (nb + q*4 + i)*DD + dc];
  __syncthreads();
  // ---- capture v delta, add bases to VN chunks (regs) and XN (in place) ----
  float voldd[4][3];
  #pragma unroll
  for (int i = 0; i < 4; i++)
    #pragma unroll
    for (int c = 0; c < 3; c++) voldd[i][c] = VN(c*16 + q*4 + i, dc);
  float4 cf[3];
  {
    int ch = tid * 3;
    #pragma unroll
    for (int j = 0; j < 3; j++) {
      int r = (ch + j) >> 5, c4 = (ch + j) & 31;
      float4 t = *(const float4*)&VN(r, c4*4);
      cf[j] = make_float4(vb4[j].x + t.x, vb4[j].y + t.y, vb4[j].z + t.z, vb4[j].w + t.w);
    }
    int r = tid >> 5, c4 = tid & 31;
    float4 t = *(float4*)&XN(r, c4*4);
    *(float4*)&XN(r, c4*4) = make_float4(xb4.x + t.x, xb4.y + t.y, xb4.z + t.z, xb4.w + t.w);
  }
  __syncthreads();                      // all fp32 reads done before short overwrite
  {
    int ch = tid * 3;
    #pragma unroll
    for (int j = 0; j < 3; j++) {
      int r = (ch + j) >> 5, c4 = (ch + j) & 31;
      split_store4(cf[j], &VNH(r, c4*4), &VNL(r, c4*4));
    }
  }
  __syncthreads();
  // ---- phase 1: U & V projections for column-slice dc (A-fragments pre-split) ----
  v4f aU[3] = {}, aV[3] = {};
  #pragma unroll
  for (int s = 0; s < 4; s++) {
    long boff = (long)dc*128 + s*32 + q*8;
    v8s buh = *(const v8s*)(Uth + boff);
    v8s bul = *(const v8s*)(Utl + boff);
    v8s bvh = *(const v8s*)(Vth + boff);
    v8s bvl = *(const v8s*)(Vtl + boff);
    #pragma unroll
    for (int c = 0; c < 3; c++) {
      v8s ah = *(const v8s*)&VNH(c*16 + l15, s*32 + q*8);
      v8s al = *(const v8s*)&VNL(c*16 + l15, s*32 + q*8);
      MFMA3(aU[c], ah, al, buh, bul);
      MFMA3(aV[c], ah, al, bvh, bvl);
    }
  }
  float sreg[4], vn2[4];
  #pragma unroll
  for (int i = 0; i < 4; i++) {
    sreg[i] = aU[0][i]*aV[0][i] + aU[1][i]*aV[1][i] + aU[2][i]*aV[2][i];
    vn2[i]  = aV[0][i]*aV[0][i] + aV[1][i]*aV[1][i] + aV[2][i]*aV[2][i];
  }
  __syncthreads();   // all reads of VNH/VNL complete before CAT overlay
  // ---- build cat = [x_new | Vn] directly as bf16 hi/lo (split once by producer) ----
  {
    int r = tid >> 5, c4 = tid & 31;   // 512 tasks: 16 rows x 32 float4-chunks
    float4 f = *(const float4*)&XN(r, c4*4);
    split_store4(f, &CATH(r, c4*4), &CATL(r, c4*4));
  }
  #pragma unroll
  for (int i = 0; i < 4; i++) {
    short h, l;
    split2(sqrtf(vn2[i] + 1e-8f), h, l);
    CATH(q*4 + i, 128 + dc) = h;
    CATL(q*4 + i, 128 + dc) = l;
  }
  __syncthreads();
  // ---- GEMM1: t2[:, dc] = silu(cat @ Wu1 + b1), K=256; t2 written pre-split ----
  {
    v4f acc = {};
    #pragma unroll
    for (int s = 0; s < 8; s++) {
      v8s ah = *(const v8s*)&CATH(l15, s*32 + q*8);
      v8s al = *(const v8s*)&CATL(l15, s*32 + q*8);
      v8s bh = *(const v8s*)(W1h + (long)dc*256 + s*32 + q*8);
      v8s bl = *(const v8s*)(W1l + (long)dc*256 + s*32 + q*8);
      MFMA3(acc, ah, al, bh, bl);
    }
    float bb = b1[dc];
    #pragma unroll
    for (int i = 0; i < 4; i++) {
      short h, l;
      split2(silu_f(acc[i] + bb), h, l);
      T2H(q*4 + i, dc) = h;
      T2L(q*4 + i, dc) = l;
    }
  }
  __syncthreads();
  // ---- GEMM2 + epilogue ----
  {
    v4f acc[3] = {};
    #pragma unroll
    for (int s = 0; s < 4; s++) {
      v8s ah = *(const v8s*)&T2H(l15, s*32 + q*8);
      v8s al = *(const v8s*)&T2L(l15, s*32 + q*8);
      #pragma unroll
      for (int g = 0; g < 3; g++) {
        int n = g*128 + dc;                 // avv: dc, asv: 128+dc, ass: 256+dc
        v8s bh = *(const v8s*)(W2h + (long)n*128 + s*32 + q*8);
        v8s bl = *(const v8s*)(W2l + (long)n*128 + s*32 + q*8);
        MFMA3(acc[g], ah, al, bh, bl);
      }
    }
    float bavv = b2[dc], basv = b2[128 + dc], bass = b2[256 + dc];
    #pragma unroll
    for (int i = 0; i < 4; i++) {
      int lr = q*4 + i;
      long row = nb + lr;
      float avv = acc[0][i] + bavv;
      float asv = acc[1][i] + basv;
      float ass = acc[2][i] + bass;
      float xf = XN(lr, dc) + ass + asv * sreg[i];
      if (!last) {
        x[row*DD + dc] = xf;
        #pragma unroll
        for (int c = 0; c < 3; c++)
          vB[(long)c*NND + row*DD + dc] = fmaf(avv, aU[c][i], voldd[i][c] + vbold[i][c]);
      } else {
        XN(lr, dc) = xf;    // keep final x row in LDS for the fused head
      }
    }
  }
  // ---- fused output head (last layer only): out += silu(x@Wo1+bo1)@Wo2 + bo2 ----
  // Vectorized: float4 LDS reads of XN + contiguous float4 reads of Wo1T rows.
  if (last) {
    __syncthreads();        // all final XN writes visible
    int r = tid >> 5, hl = tid & 31;   // 16 rows x 32 lanes; lane handles h=hl and h=hl+32
    const float* w0p = Wo1T + (long)hl * DD;
    const float* w1p = Wo1T + (long)(hl + 32) * DD;
    float a0 = bo1[hl], a1 = bo1[hl + 32];
    #pragma unroll 8
    for (int d2 = 0; d2 < DD; d2 += 4) {
      v4f xv = *(const v4f*)&XN(r, d2);
      v4f wa = *(const v4f*)(w0p + d2);
      v4f wb = *(const v4f*)(w1p + d2);
      a0 = fmaf(xv[0], wa[0], a0); a0 = fmaf(xv[1], wa[1], a0);
      a0 = fmaf(xv[2], wa[2], a0); a0 = fmaf(xv[3], wa[3], a0);
      a1 = fmaf(xv[0], wb[0], a1); a1 = fmaf(xv[1], wb[1], a1);
      a1 = fmaf(xv[2], wb[2], a1); a1 = fmaf(xv[3], wb[3], a1);
    }
    float val = silu_f(a0) * Wo2[hl] + silu_f(a1) * Wo2[hl + 32];
    #pragma unroll
    for (int off = 16; off > 0; off >>= 1) val += __shfl_down(val, off, 32);
    if (hl == 0) atomicAdd(&out[batch[nb + r]], val + bo2[0]);
  }
  #undef VN
  #undef XN
  #undef VNH
  #undef VNL
  #undef CATH
  #undef CATL
  #undef T2H
  #undef T2L
}

// ---------------- launcher ----------------
extern "C" void kernel_launch(void* const* d_in, const int* in_sizes, int n_in,
                              void* d_out, int out_size, void* d_ws, size_t ws_size,
                              hipStream_t stream) {
  const int*   at_no = (const int*)d_in[0];
  const float* pos   = (const float*)d_in[1];
  const int*   ei    = (const int*)d_in[2];
  const int*   batch = (const int*)d_in[3];
  const float* emb   = (const float*)d_in[4];
  const float* Wf    = (const float*)d_in[5];
  const float* bfp   = (const float*)d_in[6];
  const float* Wm1   = (const float*)d_in[7];
  const float* bm1   = (const float*)d_in[8];
  const float* Wm2   = (const float*)d_in[9];
  const float* bm2   = (const float*)d_in[10];
  const float* U     = (const float*)d_in[11];
  const float* V     = (const float*)d_in[12];
  const float* Wu1   = (const float*)d_in[13];
  const float* bu1   = (const float*)d_in[14];
  const float* Wu2   = (const float*)d_in[15];
  const float* bu2   = (const float*)d_in[16];
  const float* Wo1   = (const float*)d_in[17];
  const float* bo1   = (const float*)d_in[18];
  const float* Wo2   = (const float*)d_in[19];
  const float* bo2   = (const float*)d_in[20];
  float* out = (float*)d_out;

  char* w = (char*)d_ws;
  auto alloc = [&](size_t bytes) -> void* {
    void* p = (void*)w;
    w += (bytes + 255) & ~(size_t)255;
    return p;
  };
  float*  x      = (float*)alloc(sizeof(float)*(size_t)NN*DD);
  float*  v_a    = (float*)alloc(sizeof(float)*(size_t)NN*D3);   // plane layout [3][NN][DD]
  float*  v_b    = (float*)alloc(sizeof(float)*(size_t)NN*D3);
  float*  t1     = (float*)alloc(sizeof(float)*(size_t)NN*DD);   // phi slice 2
  float*  phiS   = (float*)alloc(sizeof(float)*(size_t)NN*DD);   // phi slice 1
  float*  phi0   = (float*)alloc(sizeof(float)*(size_t)NN*DD);   // phi slice 0
  short*  wbh    = (short*)alloc(sizeof(short)*(size_t)3*LSZ);   // bf16-hi weights
  short*  wbl    = (short*)alloc(sizeof(short)*(size_t)3*LSZ);   // bf16-lo weights
  int*    srcs   = (int*)alloc(sizeof(int)*(size_t)ECAP);
  float4* eg1    = (float4*)alloc(sizeof(float4)*(size_t)ECAP);
  float4* eg2    = (float4*)alloc(sizeof(float4)*(size_t)ECAP);
  int*    indptr = (int*)alloc(sizeof(int)*((size_t)NN+1));
  int*    counts = (int*)alloc(sizeof(int)*(size_t)NN);
  float*  Wo1T   = (float*)alloc(sizeof(float)*(size_t)DD*HH);   // transposed output head

  if ((size_t)(w - (char*)d_ws) > ws_size) {   // diagnostic guard: zeros => ws too small
    zero_f_kernel<<<2, 256, 0, stream>>>(out, NG_);
    return;
  }

  // NOTE: v_a zero-fill removed — layer 0 runs with first=1 and never reads vA.
  zero_f_kernel<<<2, 256, 0, stream>>>(out, NG_);
  zero_i_kernel<<<64, 256, 0, stream>>>(counts, NN);
  init_x_kernel<<<(NN*DD + 255)/256, 256, 0, stream>>>(at_no, emb, x);
  prep_w_kernel<<<(3*LSZ + 255)/256, 256, 0, stream>>>(Wm1, Wm2, U, V, Wu1, Wu2, wbh, wbl);
  prep_wo_kernel<<<(DD*HH + 255)/256, 256, 0, stream>>>(Wo1, Wo1T);
  hist_kernel<<<(NE + 255)/256, 256, 0, stream>>>(ei, pos, counts);
  scan_kernel<<<1, 1024, 0, stream>>>(counts, indptr, NN);
  zero_i_kernel<<<64, 256, 0, stream>>>(counts, NN);
  fill_kernel<<<(NE + 255)/256, 256, 0, stream>>>(ei, pos, indptr, counts, srcs, eg1, eg2);

  const int MB = (NN + 31) / 32;    // 1563
  float* vcur = v_a;
  float* vnext = v_b;
  for (int l = 0; l < 3; l++) {
    const float* Wf_l  = Wf  + (size_t)l*NB_*D3;
    const float* bf_l  = bfp + (size_t)l*D3;
    const float* bm1_l = bm1 + (size_t)l*DD;
    const float* bm2_l = bm2 + (size_t)l*D3;
    const float* bu1_l = bu1 + (size_t)l*DD;
    const float* bu2_l = bu2 + (size_t)l*D3;
    const short* Lh = wbh + (size_t)l*LSZ;
    const short* Ll = wbl + (size_t)l*LSZ;
    const short* Wm1h = Lh,          *Wm1L = Ll;
    const short* Wm2h = Lh + 16384,  *Wm2L = Ll + 16384;
    const short* Uh   = Lh + 65536,  *UL   = Ll + 65536;
    const short* Vh   = Lh + 81920,  *VL   = Ll + 81920;
    const short* Wu1h = Lh + 98304,  *Wu1L = Ll + 98304;
    const short* Wu2h = Lh + 131072, *Wu2L = Ll + 131072;

    // fused node-MLP: x -> t2 (LDS) -> phi slices {phi0, phiS, t1}
    mlp_phi_kernel<<<MB, 512, 0, stream>>>(x, Wm1h, Wm1L, bm1_l, Wm2h, Wm2L, bm2_l,
                                           phi0, phiS, t1, NN);
    // fused: edge sweep + U/V proj + a-MLP + x,v update; layer 0 skips v gathers
    // (v==0), last layer computes the output head in-block and skips dead stores
    muva_kernel<<<NN/16, 512, 0, stream>>>(phi0, phiS, t1, vcur, vnext, x,
                                           srcs, eg1, eg2, indptr, Wf_l, bf_l,
                                           Uh, UL, Vh, VL,
                                           Wu1h, Wu1L, bu1_l, Wu2h, Wu2L, bu2_l,
                                           Wo1T, bo1, Wo2, bo2, batch, out,
                                           (l == 2) ? 1 : 0, (l == 0) ? 1 : 0);

    float* tmp = vcur; vcur = vnext; vnext = tmp;
  }

  (void)in_sizes; (void)n_in; (void)out_size; (void)ws_size;
}

// Round 12
// 1253.813 us; speedup vs baseline: 1.1024x; 1.1024x over previous
//
#include <hip/hip_runtime.h>
#include <math.h>

#define NN 50000
#define NE 600000
#define ECAP 230000  // capacity for filtered edges (actual ~175K)
#define DD 128
#define D3 384
#define NB_ 20
#define HH 64
#define NG_ 512
#define LSZ 180224   // shorts per layer of transposed-bf16 weights

typedef short v8s __attribute__((ext_vector_type(8)));
typedef short v4sh __attribute__((ext_vector_type(4)));
typedef float v4f __attribute__((ext_vector_type(4)));

__device__ __forceinline__ float silu_f(float z) { return z / (1.0f + expf(-z)); }

__device__ __forceinline__ short f2bf(float f) {
  unsigned u = __float_as_uint(f);
  u += 0x7FFF + ((u >> 16) & 1);          // RNE
  return (short)(u >> 16);
}
__device__ __forceinline__ float bf2f(short s) {
  return __uint_as_float(((unsigned)(unsigned short)s) << 16);
}
__device__ __forceinline__ void split2(float x, short& h, short& l) {
  h = f2bf(x);
  l = f2bf(x - bf2f(h));
}
// split a float4 and store hi/lo as short4 (8B LDS stores)
__device__ __forceinline__ void split_store4(float4 f, short* hp, short* lp) {
  short h0,l0,h1,l1,h2,l2,h3,l3;
  split2(f.x,h0,l0); split2(f.y,h1,l1); split2(f.z,h2,l2); split2(f.w,h3,l3);
  v4sh hv = {h0,h1,h2,h3}, lv = {l0,l1,l2,l3};
  *(v4sh*)hp = hv; *(v4sh*)lp = lv;
}
// 3-term Markidis split: acc += ah@bh + al@bh + ah@bl   (proven: absmax 4.3e9)
#define MFMA3(acc, ah, al, bh, bl) \
  acc = __builtin_amdgcn_mfma_f32_16x16x32_bf16(ah, bh, acc, 0, 0, 0); \
  acc = __builtin_amdgcn_mfma_f32_16x16x32_bf16(al, bh, acc, 0, 0, 0); \
  acc = __builtin_amdgcn_mfma_f32_16x16x32_bf16(ah, bl, acc, 0, 0, 0);

// ---------------- utility ----------------
__global__ void zero_f_kernel(float* __restrict__ p, long n) {
  long i = (long)blockIdx.x * blockDim.x + threadIdx.x;
  long s = (long)gridDim.x * blockDim.x;
  for (; i < n; i += s) p[i] = 0.0f;
}

__global__ void zero_i_kernel(int* __restrict__ p, long n) {
  long i = (long)blockIdx.x * blockDim.x + threadIdx.x;
  long s = (long)gridDim.x * blockDim.x;
  for (; i < n; i += s) p[i] = 0;
}

__global__ void init_x_kernel(const int* __restrict__ at_no, const float* __restrict__ emb,
                              float* __restrict__ x) {
  int i = blockIdx.x * blockDim.x + threadIdx.x;
  if (i >= NN * DD) return;
  x[i] = emb[at_no[i >> 7] * DD + (i & 127)];
}

// ---------------- weight prep: fp32 [K][N] -> transposed bf16 hi/lo [N][K] ----------------
__global__ void prep_w_kernel(const float* __restrict__ Wm1, const float* __restrict__ Wm2,
                              const float* __restrict__ U, const float* __restrict__ V,
                              const float* __restrict__ Wu1, const float* __restrict__ Wu2,
                              short* __restrict__ hi, short* __restrict__ lo) {
  int idx = blockIdx.x * 256 + threadIdx.x;
  if (idx >= 3 * LSZ) return;
  int l = idx / LSZ, r = idx % LSZ;
  const float* src; int K, N, nk;
  if (r < 16384)       { src = Wm1 + (size_t)l*16384; K = 128; N = 128; nk = r; }
  else if (r < 65536)  { src = Wm2 + (size_t)l*49152; K = 128; N = 384; nk = r - 16384; }
  else if (r < 81920)  { src = U   + (size_t)l*16384; K = 128; N = 128; nk = r - 65536; }
  else if (r < 98304)  { src = V   + (size_t)l*16384; K = 128; N = 128; nk = r - 81920; }
  else if (r < 131072) { src = Wu1 + (size_t)l*32768; K = 256; N = 128; nk = r - 98304; }
  else                 { src = Wu2 + (size_t)l*49152; K = 128; N = 384; nk = r - 131072; }
  int n = nk / K, k = nk - n * K;
  float xx = src[(size_t)k * N + n];
  short h = f2bf(xx);
  hi[idx] = h;
  lo[idx] = f2bf(xx - bf2f(h));
}

// ---------------- CSR build (dst-sorted), filtering dist>=CUTOFF edges ----------------
__global__ void hist_kernel(const int* __restrict__ ei, const float* __restrict__ pos,
                            int* __restrict__ counts) {
  int e = blockIdx.x * blockDim.x + threadIdx.x;
  if (e >= NE) return;
  int s = ei[e], d = ei[NE + e];
  float dx = pos[3*d]   - pos[3*s];
  float dy = pos[3*d+1] - pos[3*s+1];
  float dz = pos[3*d+2] - pos[3*s+2];
  float d2 = dx*dx + dy*dy + dz*dz + 1e-12f;
  if (d2 < 25.0f) atomicAdd(&counts[d], 1);
}

__global__ void scan_kernel(const int* __restrict__ counts, int* __restrict__ indptr, int n) {
  __shared__ int sm[1024];
  __shared__ int carry_s;
  if (threadIdx.x == 0) carry_s = 0;
  __syncthreads();
  for (int start = 0; start < n; start += 1024) {
    int i = start + (int)threadIdx.x;
    int val = (i < n) ? counts[i] : 0;
    sm[threadIdx.x] = val;
    __syncthreads();
    for (int off = 1; off < 1024; off <<= 1) {
      int t = (threadIdx.x >= (unsigned)off) ? sm[threadIdx.x - off] : 0;
      __syncthreads();
      sm[threadIdx.x] += t;
      __syncthreads();
    }
    int c = carry_s;
    if (i < n) indptr[i] = c + sm[threadIdx.x] - val;
    __syncthreads();
    if (threadIdx.x == 0) carry_s = c + sm[1023];
    __syncthreads();
  }
  if (threadIdx.x == 0) indptr[n] = carry_s;
}

__global__ void fill_kernel(const int* __restrict__ ei, const float* __restrict__ pos,
                            const int* __restrict__ indptr, int* __restrict__ cursor,
                            int* __restrict__ srcs, float4* __restrict__ eg1,
                            float4* __restrict__ eg2) {
  int e = blockIdx.x * blockDim.x + threadIdx.x;
  if (e >= NE) return;
  int s = ei[e], d = ei[NE + e];
  float dx = pos[3*d]   - pos[3*s];
  float dy = pos[3*d+1] - pos[3*s+1];
  float dz = pos[3*d+2] - pos[3*s+2];
  float d2 = dx*dx + dy*dy + dz*dz + 1e-12f;
  if (d2 < 25.0f) {
    int p = atomicAdd(&cursor[d], 1);
    int slot = indptr[d] + p;
    float dist = sqrtf(d2);
    float inv = 1.0f / dist;
    float wang = 0.62831853071795864769f * dist;   // pi*dist/CUTOFF
    float s1 = __sinf(wang), c1 = __cosf(wang);
    float fc = 0.5f * (c1 + 1.0f);
    srcs[slot] = s;
    eg1[slot] = make_float4(s1, c1, fc, fc * inv);
    eg2[slot] = make_float4(dx * inv, dy * inv, dz * inv, 0.0f);
  }
}

// ---------------- fused node MLP: phi = silu(x@Wm1+b1)@Wm2+b2, tri-slice out ----------------
// Row-local chain; t2 never leaves LDS. 512 thr / 8 waves, 32 rows/block.
__global__ void __launch_bounds__(512) mlp_phi_kernel(
    const float* __restrict__ x,
    const short* __restrict__ W1h, const short* __restrict__ W1l, const float* __restrict__ b1,
    const short* __restrict__ W2h, const short* __restrict__ W2l, const float* __restrict__ b2,
    float* __restrict__ C0, float* __restrict__ C1, float* __restrict__ C2, int M) {
  __shared__ short sm[4 * 32 * 136];   // XH | XL | TH | TL
  #define XH_(r,c) sm[(r)*136 + (c)]
  #define XL_(r,c) sm[4352 + (r)*136 + (c)]
  #define TH_(r,c) sm[8704 + (r)*136 + (c)]
  #define TL_(r,c) sm[13056 + (r)*136 + (c)]
  int tid = threadIdx.x;
  long r0 = (long)blockIdx.x * 32;
  #pragma unroll
  for (int i = 0; i < 2; i++) {
    int lin = i*512 + tid;
    int r = lin >> 5, c4 = lin & 31;
    long row = r0 + r; if (row >= M) row = M - 1;
    float4 f = *(const float4*)(x + row*128 + c4*4);
    split_store4(f, &XH_(r, c4*4), &XL_(r, c4*4));
  }
  __syncthreads();
  int lane = tid & 63, wv = tid >> 6;   // wv 0..7
  int l15 = lane & 15, q = lane >> 4;
  // GEMM1: t2 = silu(x@Wm1 + b1); wave w owns cols w*16+l15
  {
    int n = wv*16 + l15;
    v4f acc[2] = {};
    #pragma unroll
    for (int s = 0; s < 4; s++) {
      v8s bh = *(const v8s*)(W1h + (long)n*128 + s*32 + q*8);
      v8s bl = *(const v8s*)(W1l + (long)n*128 + s*32 + q*8);
      #pragma unroll
      for (int mt = 0; mt < 2; mt++) {
        v8s ah = *(const v8s*)&XH_(mt*16 + l15, s*32 + q*8);
        v8s al = *(const v8s*)&XL_(mt*16 + l15, s*32 + q*8);
        MFMA3(acc[mt], ah, al, bh, bl);
      }
    }
    float bb = b1[n];
    #pragma unroll
    for (int mt = 0; mt < 2; mt++)
      #pragma unroll
      for (int i = 0; i < 4; i++) {
        short h, l;
        split2(silu_f(acc[mt][i] + bb), h, l);
        TH_(mt*16 + q*4 + i, n) = h;
        TL_(mt*16 + q*4 + i, n) = l;
      }
  }
  __syncthreads();
  // GEMM2: phi = t2@Wm2 + b2 (384 cols; wave w -> n-tiles w*3..w*3+2)
  v4f acc[2][3] = {};
  #pragma unroll
  for (int s = 0; s < 4; s++) {
    v8s ah[2], al[2];
    #pragma unroll
    for (int mt = 0; mt < 2; mt++) {
      ah[mt] = *(const v8s*)&TH_(mt*16 + l15, s*32 + q*8);
      al[mt] = *(const v8s*)&TL_(mt*16 + l15, s*32 + q*8);
    }
    #pragma unroll
    for (int j = 0; j < 3; j++) {
      int n = (wv*3 + j)*16 + l15;
      v8s bh = *(const v8s*)(W2h + (long)n*128 + s*32 + q*8);
      v8s bl = *(const v8s*)(W2l + (long)n*128 + s*32 + q*8);
      #pragma unroll
      for (int mt = 0; mt < 2; mt++) { MFMA3(acc[mt][j], ah[mt], al[mt], bh, bl); }
    }
  }
  #pragma unroll
  for (int j = 0; j < 3; j++) {
    int n = (wv*3 + j)*16 + l15;
    int sl = n >> 7, col = n & 127;
    float* C = (sl == 0) ? C0 : (sl == 1) ? C1 : C2;
    float bb = b2[n];
    #pragma unroll
    for (int mt = 0; mt < 2; mt++)
      #pragma unroll
      for (int i = 0; i < 4; i++) {
        long row = r0 + mt*16 + q*4 + i;
        if (row < M) C[row*128 + col] = acc[mt][j][i] + bb;
      }
  }
  #undef XH_
  #undef XL_
  #undef TH_
  #undef TL_
}

// ---------------- FUSED message pass + Uv/Vv/Vn/s + a-MLP + update (muva, R25) ----------------
// R25 = R18 structure, TEMPLATED on <FIRST, LAST> so each layer's instantiation is
// branch-free (R24's runtime flags raised VGPR 56->64 on ALL layers):
//  - FIRST=1 (layer 0): v==0 -> v gather/base reads constant-folded away.
//  - LAST=1 (layer 2): skip dead x/v stores; fused output head with COALESCED
//    original-layout Wo1 reads: lane<->h (64 lanes = 64 h), wave<->2 rows; per d:
//    one 256B-coalesced Wo1 row load + LDS broadcast of XN + 2 fma. (R24's Wo1T
//    variant read 64 distinct cache lines per instruction -> +113us. Access-pattern
//    arithmetic first, instruction count second.)
template<int FIRST, int LAST>
__global__ void __launch_bounds__(512, 3) muva_kernel(
    const float* __restrict__ phi0, const float* __restrict__ phi1,
    const float* __restrict__ phi2, const float* __restrict__ vA,
    float* __restrict__ vB, float* __restrict__ x,
    const int* __restrict__ srcs, const float4* __restrict__ eg1,
    const float4* __restrict__ eg2, const int* __restrict__ indptr,
    const float* __restrict__ Wf_l, const float* __restrict__ bf_l,
    const short* __restrict__ Uth, const short* __restrict__ Utl,
    const short* __restrict__ Vth, const short* __restrict__ Vtl,
    const short* __restrict__ W1h, const short* __restrict__ W1l, const float* __restrict__ b1,
    const short* __restrict__ W2h, const short* __restrict__ W2l, const float* __restrict__ b2,
    const float* __restrict__ Wo1, const float* __restrict__ bo1,
    const float* __restrict__ Wo2, const float* __restrict__ bo2,
    const int* __restrict__ batch, float* __restrict__ out) {
  __shared__ float smem[8896];   // 35584 B
  // region A floats [0,6720): VN [48][140] fp32 deltas during sweep,
  //   then converted IN PLACE to shorts: VNH[48][136] @0 | VNL[48][136] @6528
  //   then overlaid by CATH[16][264] @0 | CATL @4224 | T2H[16][136] @8448 | T2L @10624
  // region B floats [6720,8896): XN [16][136] fp32 (delta then full; intact until epilogue;
  //   on last layer holds FINAL x rows for the fused output head)
  short* sms = (short*)smem;
  #define VN(r,c)   smem[(r)*140 + (c)]
  #define XN(r,c)   smem[6720 + (r)*136 + (c)]
  #define VNH(r,c)  sms[(r)*136 + (c)]
  #define VNL(r,c)  sms[6528 + (r)*136 + (c)]
  #define CATH(r,c) sms[(r)*264 + (c)]
  #define CATL(r,c) sms[4224 + (r)*264 + (c)]
  #define T2H(r,c)  sms[8448 + (r)*136 + (c)]
  #define T2L(r,c)  sms[10624 + (r)*136 + (c)]
  const long NND = (long)NN*DD;
  int tid = threadIdx.x;
  long nb = (long)blockIdx.x * 16;
  // ---- phase E: edge sweep. 4 groups x 128 d-lanes; group g handles nodes 4g..4g+3 ----
  {
    int gs = __builtin_amdgcn_readfirstlane((int)(tid >> 7));   // wave-uniform group id
    int d  = tid & 127;
    float wf0[NB_], wf1[NB_], wf2[NB_];
    #pragma unroll
    for (int k = 0; k < NB_; k++) {
      wf0[k] = Wf_l[k*D3 + d];
      wf1[k] = Wf_l[k*D3 + DD + d];
      wf2[k] = Wf_l[k*D3 + 2*DD + d];
    }
    // pin: make each wf value an asm output -> not rematerializable (R18 behavior kept)
    #pragma unroll
    for (int k = 0; k < NB_; k++) {
      asm volatile("" : "+v"(wf0[k]), "+v"(wf1[k]), "+v"(wf2[k]));
    }
    float bf0 = bf_l[d], bf1 = bf_l[DD + d], bf2 = bf_l[2*DD + d];
    long n0g = nb + 4*gs;
    int b0  = __builtin_amdgcn_readfirstlane(indptr[n0g]);
    int b1_ = __builtin_amdgcn_readfirstlane(indptr[n0g+1]);
    int b2_ = __builtin_amdgcn_readfirstlane(indptr[n0g+2]);
    int b3_ = __builtin_amdgcn_readfirstlane(indptr[n0g+3]);
    int b4_ = __builtin_amdgcn_readfirstlane(indptr[n0g+4]);
    // pipeline state: slot A/B = {per-lane gathers, uniform geometry}; src ring 4 ahead
    int sA = 0, sB = 0;
    float p0A=0,p1A=0,p2A=0,w0A=0,w1A=0,w2A=0;
    float p0B=0,p1B=0,p2B=0,w0B=0,w1B=0,w2B=0;
    float4 g1A={}, g2A={}, g1B={}, g2B={};
    if (b0 < b4_) {
      int s0 = srcs[b0];
      long bb = (long)s0*DD + d;
      p0A = phi0[bb]; p1A = phi1[bb]; p2A = phi2[bb];
      if (!FIRST) { w0A = vA[bb]; w1A = vA[NND+bb]; w2A = vA[2*NND+bb]; }
      g1A = eg1[b0]; g2A = eg2[b0];
    }
    if (b0 + 1 < b4_) {
      int s1v = srcs[b0+1];
      long bb = (long)s1v*DD + d;
      p0B = phi0[bb]; p1B = phi1[bb]; p2B = phi2[bb];
      if (!FIRST) { w0B = vA[bb]; w1B = vA[NND+bb]; w2B = vA[2*NND+bb]; }
      g1B = eg1[b0+1]; g2B = eg2[b0+1];
    }
    if (b0 + 2 < b4_) sA = srcs[b0+2];
    if (b0 + 3 < b4_) sB = srcs[b0+3];
    float xacc=0.f, a0=0.f, a1=0.f, a2=0.f;
    int e = b0, cur = 0, nxt = b1_;
    // body: flush-check -> compute slot -> refill same slot for e+2 (no moves) -> src e+4
#define SW_BODY(P0,P1,P2,W0,W1,W2, G1, G2, SS) \
    { while (e >= nxt) { int nr = 4*gs + cur; \
        XN(nr, d) = xacc; VN(nr, d) = a0; VN(16+nr, d) = a1; VN(32+nr, d) = a2; \
        xacc = 0.f; a0 = 0.f; a1 = 0.f; a2 = 0.f; \
        cur++; nxt = (cur == 1) ? b2_ : (cur == 2) ? b3_ : b4_; } \
      float c2 = 2.0f * G1.y; \
      float rkm1 = 0.f, rk = G1.x, dot0 = 0.f, dot1 = 0.f, dot2 = 0.f; \
      _Pragma("unroll") \
      for (int k = 0; k < NB_; k++) { \
        dot0 = fmaf(rk, wf0[k], dot0); \
        dot1 = fmaf(rk, wf1[k], dot1); \
        dot2 = fmaf(rk, wf2[k], dot2); \
        float rn = fmaf(c2, rk, -rkm1); \
        rkm1 = rk; rk = rn; } \
      xacc = fmaf(P0, bf0*G1.z + G1.w*dot0, xacc); \
      float m1 = P1 * (bf1*G1.z + G1.w*dot1); \
      float m2 = P2 * (bf2*G1.z + G1.w*dot2); \
      a0 = fmaf(m1, G2.x, fmaf(m2, W0, a0)); \
      a1 = fmaf(m1, G2.y, fmaf(m2, W1, a1)); \
      a2 = fmaf(m1, G2.z, fmaf(m2, W2, a2)); \
      if (e + 2 < b4_) { \
        long bb = (long)SS*DD + d; \
        P0 = phi0[bb]; P1 = phi1[bb]; P2 = phi2[bb]; \
        if (!FIRST) { W0 = vA[bb]; W1 = vA[NND+bb]; W2 = vA[2*NND+bb]; } \
        G1 = eg1[e+2]; G2 = eg2[e+2]; } \
      if (e + 4 < b4_) SS = srcs[e+4]; \
      ++e; }
    while (e < b4_) {
      SW_BODY(p0A,p1A,p2A,w0A,w1A,w2A, g1A, g2A, sA)
      if (e >= b4_) break;
      SW_BODY(p0B,p1B,p2B,w0B,w1B,w2B, g1B, g2B, sB)
    }
#undef SW_BODY
    while (cur < 4) {
      int nr = 4*gs + cur;
      XN(nr, d) = xacc; VN(nr, d) = a0; VN(16+nr, d) = a1; VN(32+nr, d) = a2;
      xacc = 0.f; a0 = 0.f; a1 = 0.f; a2 = 0.f;
      cur++;
    }
  }
  // ---- issue base-row loads BEFORE the barrier (overlap with sweep stragglers) ----
  int lane = tid & 63, wv = tid >> 6;   // wv 0..7
  int l15 = lane & 15, q = lane >> 4;
  int dc = wv*16 + l15;                 // this wave's column slice
  float4 vb4[3]; float4 xb4;
  {
    int ch = tid * 3;                   // 1536 float4-chunks: 48 rows x 32
    #pragma unroll
    for (int j = 0; j < 3; j++) {
      if (!FIRST) {
        int r = (ch + j) >> 5, c4 = (ch + j) & 31;
        vb4[j] = *(const float4*)(vA + (long)(r >> 4)*NND + (nb + (r & 15))*DD + c4*4);
      } else {
        vb4[j] = make_float4(0.f, 0.f, 0.f, 0.f);
      }
    }
    int r = tid >> 5, c4 = tid & 31;
    xb4 = *(const float4*)(x + (nb + r)*DD + c4*4);
  }
  float vbold[4][3];
  #pragma unroll
  for (int i = 0; i < 4; i++)
    #pragma unroll
    for (int c = 0; c < 3; c++)
      vbold[i][c] = FIRST ? 0.f : vA[(long)c*NND + (nb + q*4 + i)*DD + dc];
  __syncthreads();
  // ---- capture v delta, add bases to VN chunks (regs) and XN (in place) ----
  float voldd[4][3];
  #pragma unroll
  for (int i = 0; i < 4; i++)
    #pragma unroll
    for (int c = 0; c < 3; c++) voldd[i][c] = VN(c*16 + q*4 + i, dc);
  float4 cf[3];
  {
    int ch = tid * 3;
    #pragma unroll
    for (int j = 0; j < 3; j++) {
      int r = (ch + j) >> 5, c4 = (ch + j) & 31;
      float4 t = *(const float4*)&VN(r, c4*4);
      cf[j] = make_float4(vb4[j].x + t.x, vb4[j].y + t.y, vb4[j].z + t.z, vb4[j].w + t.w);
    }
    int r = tid >> 5, c4 = tid & 31;
    float4 t = *(float4*)&XN(r, c4*4);
    *(float4*)&XN(r, c4*4) = make_float4(xb4.x + t.x, xb4.y + t.y, xb4.z + t.z, xb4.w + t.w);
  }
  __syncthreads();                      // all fp32 reads done before short overwrite
  {
    int ch = tid * 3;
    #pragma unroll
    for (int j = 0; j < 3; j++) {
      int r = (ch + j) >> 5, c4 = (ch + j) & 31;
      split_store4(cf[j], &VNH(r, c4*4), &VNL(r, c4*4));
    }
  }
  __syncthreads();
  // ---- phase 1: U & V projections for column-slice dc (A-fragments pre-split) ----
  v4f aU[3] = {}, aV[3] = {};
  #pragma unroll
  for (int s = 0; s < 4; s++) {
    long boff = (long)dc*128 + s*32 + q*8;
    v8s buh = *(const v8s*)(Uth + boff);
    v8s bul = *(const v8s*)(Utl + boff);
    v8s bvh = *(const v8s*)(Vth + boff);
    v8s bvl = *(const v8s*)(Vtl + boff);
    #pragma unroll
    for (int c = 0; c < 3; c++) {
      v8s ah = *(const v8s*)&VNH(c*16 + l15, s*32 + q*8);
      v8s al = *(const v8s*)&VNL(c*16 + l15, s*32 + q*8);
      MFMA3(aU[c], ah, al, buh, bul);
      MFMA3(aV[c], ah, al, bvh, bvl);
    }
  }
  float sreg[4], vn2[4];
  #pragma unroll
  for (int i = 0; i < 4; i++) {
    sreg[i] = aU[0][i]*aV[0][i] + aU[1][i]*aV[1][i] + aU[2][i]*aV[2][i];
    vn2[i]  = aV[0][i]*aV[0][i] + aV[1][i]*aV[1][i] + aV[2][i]*aV[2][i];
  }
  __syncthreads();   // all reads of VNH/VNL complete before CAT overlay
  // ---- build cat = [x_new | Vn] directly as bf16 hi/lo (split once by producer) ----
  {
    int r = tid >> 5, c4 = tid & 31;   // 512 tasks: 16 rows x 32 float4-chunks
    float4 f = *(const float4*)&XN(r, c4*4);
    split_store4(f, &CATH(r, c4*4), &CATL(r, c4*4));
  }
  #pragma unroll
  for (int i = 0; i < 4; i++) {
    short h, l;
    split2(sqrtf(vn2[i] + 1e-8f), h, l);
    CATH(q*4 + i, 128 + dc) = h;
    CATL(q*4 + i, 128 + dc) = l;
  }
  __syncthreads();
  // ---- GEMM1: t2[:, dc] = silu(cat @ Wu1 + b1), K=256; t2 written pre-split ----
  {
    v4f acc = {};
    #pragma unroll
    for (int s = 0; s < 8; s++) {
      v8s ah = *(const v8s*)&CATH(l15, s*32 + q*8);
      v8s al = *(const v8s*)&CATL(l15, s*32 + q*8);
      v8s bh = *(const v8s*)(W1h + (long)dc*256 + s*32 + q*8);
      v8s bl = *(const v8s*)(W1l + (long)dc*256 + s*32 + q*8);
      MFMA3(acc, ah, al, bh, bl);
    }
    float bb = b1[dc];
    #pragma unroll
    for (int i = 0; i < 4; i++) {
      short h, l;
      split2(silu_f(acc[i] + bb), h, l);
      T2H(q*4 + i, dc) = h;
      T2L(q*4 + i, dc) = l;
    }
  }
  __syncthreads();
  // ---- GEMM2 + epilogue ----
  {
    v4f acc[3] = {};
    #pragma unroll
    for (int s = 0; s < 4; s++) {
      v8s ah = *(const v8s*)&T2H(l15, s*32 + q*8);
      v8s al = *(const v8s*)&T2L(l15, s*32 + q*8);
      #pragma unroll
      for (int g = 0; g < 3; g++) {
        int n = g*128 + dc;                 // avv: dc, asv: 128+dc, ass: 256+dc
        v8s bh = *(const v8s*)(W2h + (long)n*128 + s*32 + q*8);
        v8s bl = *(const v8s*)(W2l + (long)n*128 + s*32 + q*8);
        MFMA3(acc[g], ah, al, bh, bl);
      }
    }
    float bavv = b2[dc], basv = b2[128 + dc], bass = b2[256 + dc];
    #pragma unroll
    for (int i = 0; i < 4; i++) {
      int lr = q*4 + i;
      long row = nb + lr;
      float avv = acc[0][i] + bavv;
      float asv = acc[1][i] + basv;
      float ass = acc[2][i] + bass;
      float xf = XN(lr, dc) + ass + asv * sreg[i];
      if (!LAST) {
        x[row*DD + dc] = xf;
        #pragma unroll
        for (int c = 0; c < 3; c++)
          vB[(long)c*NND + row*DD + dc] = fmaf(avv, aU[c][i], voldd[i][c] + vbold[i][c]);
      } else {
        XN(lr, dc) = xf;    // keep final x row in LDS for the fused head
      }
    }
  }
  // ---- fused output head (LAST only): out += silu(x@Wo1+bo1)@Wo2 + bo2 ----
  // lane<->h (64 lanes = 64 h-channels), wave<->2 rows. Per d: one coalesced 256B
  // Wo1 row load (lanes->consecutive floats) + LDS broadcast of XN + 2 fma.
  if (LAST) {
    __syncthreads();        // all final XN writes visible
    float bo1v = bo1[lane];
    float wo2v = Wo2[lane];
    int r0_ = wv * 2, r1_ = r0_ + 1;
    float acc0 = bo1v, acc1 = bo1v;
    #pragma unroll 8
    for (int d2 = 0; d2 < DD; d2++) {
      float wv_ = Wo1[d2*HH + lane];   // 64 lanes x 4B consecutive = coalesced
      acc0 = fmaf(XN(r0_, d2), wv_, acc0);   // LDS broadcast (uniform addr)
      acc1 = fmaf(XN(r1_, d2), wv_, acc1);
    }
    float v0 = silu_f(acc0) * wo2v;
    float v1 = silu_f(acc1) * wo2v;
    #pragma unroll
    for (int off = 32; off > 0; off >>= 1) {
      v0 += __shfl_down(v0, off);
      v1 += __shfl_down(v1, off);
    }
    if (lane == 0) {
      atomicAdd(&out[batch[nb + r0_]], v0 + bo2[0]);
      atomicAdd(&out[batch[nb + r1_]], v1 + bo2[0]);
    }
  }
  #undef VN
  #undef XN
  #undef VNH
  #undef VNL
  #undef CATH
  #undef CATL
  #undef T2H
  #undef T2L
}

// ---------------- launcher ----------------
extern "C" void kernel_launch(void* const* d_in, const int* in_sizes, int n_in,
                              void* d_out, int out_size, void* d_ws, size_t ws_size,
                              hipStream_t stream) {
  const int*   at_no = (const int*)d_in[0];
  const float* pos   = (const float*)d_in[1];
  const int*   ei    = (const int*)d_in[2];
  const int*   batch = (const int*)d_in[3];
  const float* emb   = (const float*)d_in[4];
  const float* Wf    = (const float*)d_in[5];
  const float* bfp   = (const float*)d_in[6];
  const float* Wm1   = (const float*)d_in[7];
  const float* bm1   = (const float*)d_in[8];
  const float* Wm2   = (const float*)d_in[9];
  const float* bm2   = (const float*)d_in[10];
  const float* U     = (const float*)d_in[11];
  const float* V     = (const float*)d_in[12];
  const float* Wu1   = (const float*)d_in[13];
  const float* bu1   = (const float*)d_in[14];
  const float* Wu2   = (const float*)d_in[15];
  const float* bu2   = (const float*)d_in[16];
  const float* Wo1   = (const float*)d_in[17];
  const float* bo1   = (const float*)d_in[18];
  const float* Wo2   = (const float*)d_in[19];
  const float* bo2   = (const float*)d_in[20];
  float* out = (float*)d_out;

  char* w = (char*)d_ws;
  auto alloc = [&](size_t bytes) -> void* {
    void* p = (void*)w;
    w += (bytes + 255) & ~(size_t)255;
    return p;
  };
  float*  x      = (float*)alloc(sizeof(float)*(size_t)NN*DD);
  float*  v_a    = (float*)alloc(sizeof(float)*(size_t)NN*D3);   // plane layout [3][NN][DD]
  float*  v_b    = (float*)alloc(sizeof(float)*(size_t)NN*D3);
  float*  t1     = (float*)alloc(sizeof(float)*(size_t)NN*DD);   // phi slice 2
  float*  phiS   = (float*)alloc(sizeof(float)*(size_t)NN*DD);   // phi slice 1
  float*  phi0   = (float*)alloc(sizeof(float)*(size_t)NN*DD);   // phi slice 0
  short*  wbh    = (short*)alloc(sizeof(short)*(size_t)3*LSZ);   // bf16-hi weights
  short*  wbl    = (short*)alloc(sizeof(short)*(size_t)3*LSZ);   // bf16-lo weights
  int*    srcs   = (int*)alloc(sizeof(int)*(size_t)ECAP);
  float4* eg1    = (float4*)alloc(sizeof(float4)*(size_t)ECAP);
  float4* eg2    = (float4*)alloc(sizeof(float4)*(size_t)ECAP);
  int*    indptr = (int*)alloc(sizeof(int)*((size_t)NN+1));
  int*    counts = (int*)alloc(sizeof(int)*(size_t)NN);

  if ((size_t)(w - (char*)d_ws) > ws_size) {   // diagnostic guard: zeros => ws too small
    zero_f_kernel<<<2, 256, 0, stream>>>(out, NG_);
    return;
  }

  // NOTE: v_a zero-fill not needed — layer 0 runs FIRST=1 and never reads vA.
  zero_f_kernel<<<2, 256, 0, stream>>>(out, NG_);
  zero_i_kernel<<<64, 256, 0, stream>>>(counts, NN);
  init_x_kernel<<<(NN*DD + 255)/256, 256, 0, stream>>>(at_no, emb, x);
  prep_w_kernel<<<(3*LSZ + 255)/256, 256, 0, stream>>>(Wm1, Wm2, U, V, Wu1, Wu2, wbh, wbl);
  hist_kernel<<<(NE + 255)/256, 256, 0, stream>>>(ei, pos, counts);
  scan_kernel<<<1, 1024, 0, stream>>>(counts, indptr, NN);
  zero_i_kernel<<<64, 256, 0, stream>>>(counts, NN);
  fill_kernel<<<(NE + 255)/256, 256, 0, stream>>>(ei, pos, indptr, counts, srcs, eg1, eg2);

  const int MB = (NN + 31) / 32;    // 1563
  float* vcur = v_a;
  float* vnext = v_b;
  for (int l = 0; l < 3; l++) {
    const float* Wf_l  = Wf  + (size_t)l*NB_*D3;
    const float* bf_l  = bfp + (size_t)l*D3;
    const float* bm1_l = bm1 + (size_t)l*DD;
    const float* bm2_l = bm2 + (size_t)l*D3;
    const float* bu1_l = bu1 + (size_t)l*DD;
    const float* bu2_l = bu2 + (size_t)l*D3;
    const short* Lh = wbh + (size_t)l*LSZ;
    const short* Ll = wbl + (size_t)l*LSZ;
    const short* Wm1h = Lh,          *Wm1L = Ll;
    const short* Wm2h = Lh + 16384,  *Wm2L = Ll + 16384;
    const short* Uh   = Lh + 65536,  *UL   = Ll + 65536;
    const short* Vh   = Lh + 81920,  *VL   = Ll + 81920;
    const short* Wu1h = Lh + 98304,  *Wu1L = Ll + 98304;
    const short* Wu2h = Lh + 131072, *Wu2L = Ll + 131072;

    // fused node-MLP: x -> t2 (LDS) -> phi slices {phi0, phiS, t1}
    mlp_phi_kernel<<<MB, 512, 0, stream>>>(x, Wm1h, Wm1L, bm1_l, Wm2h, Wm2L, bm2_l,
                                           phi0, phiS, t1, NN);
    // fused: edge sweep + U/V proj + a-MLP + x,v update; templated per layer
    if (l == 0) {
      muva_kernel<1,0><<<NN/16, 512, 0, stream>>>(phi0, phiS, t1, vcur, vnext, x,
                                                  srcs, eg1, eg2, indptr, Wf_l, bf_l,
                                                  Uh, UL, Vh, VL,
                                                  Wu1h, Wu1L, bu1_l, Wu2h, Wu2L, bu2_l,
                                                  Wo1, bo1, Wo2, bo2, batch, out);
    } else if (l == 1) {
      muva_kernel<0,0><<<NN/16, 512, 0, stream>>>(phi0, phiS, t1, vcur, vnext, x,
                                                  srcs, eg1, eg2, indptr, Wf_l, bf_l,
                                                  Uh, UL, Vh, VL,
                                                  Wu1h, Wu1L, bu1_l, Wu2h, Wu2L, bu2_l,
                                                  Wo1, bo1, Wo2, bo2, batch, out);
    } else {
      muva_kernel<0,1><<<NN/16, 512, 0, stream>>>(phi0, phiS, t1, vcur, vnext, x,
                                                  srcs, eg1, eg2, indptr, Wf_l, bf_l,
                                                  Uh, UL, Vh, VL,
                                                  Wu1h, Wu1L, bu1_l, Wu2h, Wu2L, bu2_l,
                                                  Wo1, bo1, Wo2, bo2, batch, out);
    }

    float* tmp = vcur; vcur = vnext; vnext = tmp;
  }

  (void)in_sizes; (void)n_in; (void)out_size; (void)ws_size;
}

// Round 13
// 1249.333 us; speedup vs baseline: 1.1064x; 1.0036x over previous
//
#include <hip/hip_runtime.h>
#include <math.h>

#define NN 50000
#define NE 600000
#define ECAP 230000  // capacity for filtered edges (actual ~175K)
#define DD 128
#define D3 384
#define NB_ 20
#define HH 64
#define NG_ 512
#define LSZ 180224   // shorts per layer of transposed-bf16 weights

typedef short v8s __attribute__((ext_vector_type(8)));
typedef short v4sh __attribute__((ext_vector_type(4)));
typedef float v4f __attribute__((ext_vector_type(4)));

__device__ __forceinline__ float silu_f(float z) { return z / (1.0f + expf(-z)); }

__device__ __forceinline__ short f2bf(float f) {
  unsigned u = __float_as_uint(f);
  u += 0x7FFF + ((u >> 16) & 1);          // RNE
  return (short)(u >> 16);
}
__device__ __forceinline__ float bf2f(short s) {
  return __uint_as_float(((unsigned)(unsigned short)s) << 16);
}
__device__ __forceinline__ void split2(float x, short& h, short& l) {
  h = f2bf(x);
  l = f2bf(x - bf2f(h));
}
// split a float4 and store hi/lo as short4 (8B LDS stores)
__device__ __forceinline__ void split_store4(float4 f, short* hp, short* lp) {
  short h0,l0,h1,l1,h2,l2,h3,l3;
  split2(f.x,h0,l0); split2(f.y,h1,l1); split2(f.z,h2,l2); split2(f.w,h3,l3);
  v4sh hv = {h0,h1,h2,h3}, lv = {l0,l1,l2,l3};
  *(v4sh*)hp = hv; *(v4sh*)lp = lv;
}
// 3-term Markidis split: acc += ah@bh + al@bh + ah@bl   (proven: absmax 4.3e9)
#define MFMA3(acc, ah, al, bh, bl) \
  acc = __builtin_amdgcn_mfma_f32_16x16x32_bf16(ah, bh, acc, 0, 0, 0); \
  acc = __builtin_amdgcn_mfma_f32_16x16x32_bf16(al, bh, acc, 0, 0, 0); \
  acc = __builtin_amdgcn_mfma_f32_16x16x32_bf16(ah, bl, acc, 0, 0, 0);

// ---------------- utility ----------------
__global__ void zero_f_kernel(float* __restrict__ p, long n) {
  long i = (long)blockIdx.x * blockDim.x + threadIdx.x;
  long s = (long)gridDim.x * blockDim.x;
  for (; i < n; i += s) p[i] = 0.0f;
}

__global__ void zero_i_kernel(int* __restrict__ p, long n) {
  long i = (long)blockIdx.x * blockDim.x + threadIdx.x;
  long s = (long)gridDim.x * blockDim.x;
  for (; i < n; i += s) p[i] = 0;
}

__global__ void init_x_kernel(const int* __restrict__ at_no, const float* __restrict__ emb,
                              float* __restrict__ x) {
  int i = blockIdx.x * blockDim.x + threadIdx.x;
  if (i >= NN * DD) return;
  x[i] = emb[at_no[i >> 7] * DD + (i & 127)];
}

// ---------------- weight prep: fp32 [K][N] -> transposed bf16 hi/lo [N][K] ----------------
__global__ void prep_w_kernel(const float* __restrict__ Wm1, const float* __restrict__ Wm2,
                              const float* __restrict__ U, const float* __restrict__ V,
                              const float* __restrict__ Wu1, const float* __restrict__ Wu2,
                              short* __restrict__ hi, short* __restrict__ lo) {
  int idx = blockIdx.x * 256 + threadIdx.x;
  if (idx >= 3 * LSZ) return;
  int l = idx / LSZ, r = idx % LSZ;
  const float* src; int K, N, nk;
  if (r < 16384)       { src = Wm1 + (size_t)l*16384; K = 128; N = 128; nk = r; }
  else if (r < 65536)  { src = Wm2 + (size_t)l*49152; K = 128; N = 384; nk = r - 16384; }
  else if (r < 81920)  { src = U   + (size_t)l*16384; K = 128; N = 128; nk = r - 65536; }
  else if (r < 98304)  { src = V   + (size_t)l*16384; K = 128; N = 128; nk = r - 81920; }
  else if (r < 131072) { src = Wu1 + (size_t)l*32768; K = 256; N = 128; nk = r - 98304; }
  else                 { src = Wu2 + (size_t)l*49152; K = 128; N = 384; nk = r - 131072; }
  int n = nk / K, k = nk - n * K;
  float xx = src[(size_t)k * N + n];
  short h = f2bf(xx);
  hi[idx] = h;
  lo[idx] = f2bf(xx - bf2f(h));
}

// Wo1 prep: fp32 [DD][HH] -> transposed bf16 hi/lo [HH][DD] (same layout as other weights)
__global__ void prep_wo_kernel(const float* __restrict__ Wo1,
                               short* __restrict__ hi, short* __restrict__ lo) {
  int idx = blockIdx.x * 256 + threadIdx.x;
  if (idx >= HH * DD) return;
  int n = idx >> 7, k = idx & 127;
  float xx = Wo1[(size_t)k * HH + n];
  short h = f2bf(xx);
  hi[idx] = h;
  lo[idx] = f2bf(xx - bf2f(h));
}

// ---------------- CSR build (dst-sorted), filtering dist>=CUTOFF edges ----------------
__global__ void hist_kernel(const int* __restrict__ ei, const float* __restrict__ pos,
                            int* __restrict__ counts) {
  int e = blockIdx.x * blockDim.x + threadIdx.x;
  if (e >= NE) return;
  int s = ei[e], d = ei[NE + e];
  float dx = pos[3*d]   - pos[3*s];
  float dy = pos[3*d+1] - pos[3*s+1];
  float dz = pos[3*d+2] - pos[3*s+2];
  float d2 = dx*dx + dy*dy + dz*dz + 1e-12f;
  if (d2 < 25.0f) atomicAdd(&counts[d], 1);
}

__global__ void scan_kernel(const int* __restrict__ counts, int* __restrict__ indptr, int n) {
  __shared__ int sm[1024];
  __shared__ int carry_s;
  if (threadIdx.x == 0) carry_s = 0;
  __syncthreads();
  for (int start = 0; start < n; start += 1024) {
    int i = start + (int)threadIdx.x;
    int val = (i < n) ? counts[i] : 0;
    sm[threadIdx.x] = val;
    __syncthreads();
    for (int off = 1; off < 1024; off <<= 1) {
      int t = (threadIdx.x >= (unsigned)off) ? sm[threadIdx.x - off] : 0;
      __syncthreads();
      sm[threadIdx.x] += t;
      __syncthreads();
    }
    int c = carry_s;
    if (i < n) indptr[i] = c + sm[threadIdx.x] - val;
    __syncthreads();
    if (threadIdx.x == 0) carry_s = c + sm[1023];
    __syncthreads();
  }
  if (threadIdx.x == 0) indptr[n] = carry_s;
}

__global__ void fill_kernel(const int* __restrict__ ei, const float* __restrict__ pos,
                            const int* __restrict__ indptr, int* __restrict__ cursor,
                            int* __restrict__ srcs, float4* __restrict__ eg1,
                            float4* __restrict__ eg2) {
  int e = blockIdx.x * blockDim.x + threadIdx.x;
  if (e >= NE) return;
  int s = ei[e], d = ei[NE + e];
  float dx = pos[3*d]   - pos[3*s];
  float dy = pos[3*d+1] - pos[3*s+1];
  float dz = pos[3*d+2] - pos[3*s+2];
  float d2 = dx*dx + dy*dy + dz*dz + 1e-12f;
  if (d2 < 25.0f) {
    int p = atomicAdd(&cursor[d], 1);
    int slot = indptr[d] + p;
    float dist = sqrtf(d2);
    float inv = 1.0f / dist;
    float wang = 0.62831853071795864769f * dist;   // pi*dist/CUTOFF
    float s1 = __sinf(wang), c1 = __cosf(wang);
    float fc = 0.5f * (c1 + 1.0f);
    srcs[slot] = s;
    eg1[slot] = make_float4(s1, c1, fc, fc * inv);
    eg2[slot] = make_float4(dx * inv, dy * inv, dz * inv, 0.0f);
  }
}

// ---------------- fused node MLP: phi = silu(x@Wm1+b1)@Wm2+b2, tri-slice out ----------------
// Row-local chain; t2 never leaves LDS. 512 thr / 8 waves, 32 rows/block.
__global__ void __launch_bounds__(512) mlp_phi_kernel(
    const float* __restrict__ x,
    const short* __restrict__ W1h, const short* __restrict__ W1l, const float* __restrict__ b1,
    const short* __restrict__ W2h, const short* __restrict__ W2l, const float* __restrict__ b2,
    float* __restrict__ C0, float* __restrict__ C1, float* __restrict__ C2, int M) {
  __shared__ short sm[4 * 32 * 136];   // XH | XL | TH | TL
  #define XH_(r,c) sm[(r)*136 + (c)]
  #define XL_(r,c) sm[4352 + (r)*136 + (c)]
  #define TH_(r,c) sm[8704 + (r)*136 + (c)]
  #define TL_(r,c) sm[13056 + (r)*136 + (c)]
  int tid = threadIdx.x;
  long r0 = (long)blockIdx.x * 32;
  #pragma unroll
  for (int i = 0; i < 2; i++) {
    int lin = i*512 + tid;
    int r = lin >> 5, c4 = lin & 31;
    long row = r0 + r; if (row >= M) row = M - 1;
    float4 f = *(const float4*)(x + row*128 + c4*4);
    split_store4(f, &XH_(r, c4*4), &XL_(r, c4*4));
  }
  __syncthreads();
  int lane = tid & 63, wv = tid >> 6;   // wv 0..7
  int l15 = lane & 15, q = lane >> 4;
  // GEMM1: t2 = silu(x@Wm1 + b1); wave w owns cols w*16+l15
  {
    int n = wv*16 + l15;
    v4f acc[2] = {};
    #pragma unroll
    for (int s = 0; s < 4; s++) {
      v8s bh = *(const v8s*)(W1h + (long)n*128 + s*32 + q*8);
      v8s bl = *(const v8s*)(W1l + (long)n*128 + s*32 + q*8);
      #pragma unroll
      for (int mt = 0; mt < 2; mt++) {
        v8s ah = *(const v8s*)&XH_(mt*16 + l15, s*32 + q*8);
        v8s al = *(const v8s*)&XL_(mt*16 + l15, s*32 + q*8);
        MFMA3(acc[mt], ah, al, bh, bl);
      }
    }
    float bb = b1[n];
    #pragma unroll
    for (int mt = 0; mt < 2; mt++)
      #pragma unroll
      for (int i = 0; i < 4; i++) {
        short h, l;
        split2(silu_f(acc[mt][i] + bb), h, l);
        TH_(mt*16 + q*4 + i, n) = h;
        TL_(mt*16 + q*4 + i, n) = l;
      }
  }
  __syncthreads();
  // GEMM2: phi = t2@Wm2 + b2 (384 cols; wave w -> n-tiles w*3..w*3+2)
  v4f acc[2][3] = {};
  #pragma unroll
  for (int s = 0; s < 4; s++) {
    v8s ah[2], al[2];
    #pragma unroll
    for (int mt = 0; mt < 2; mt++) {
      ah[mt] = *(const v8s*)&TH_(mt*16 + l15, s*32 + q*8);
      al[mt] = *(const v8s*)&TL_(mt*16 + l15, s*32 + q*8);
    }
    #pragma unroll
    for (int j = 0; j < 3; j++) {
      int n = (wv*3 + j)*16 + l15;
      v8s bh = *(const v8s*)(W2h + (long)n*128 + s*32 + q*8);
      v8s bl = *(const v8s*)(W2l + (long)n*128 + s*32 + q*8);
      #pragma unroll
      for (int mt = 0; mt < 2; mt++) { MFMA3(acc[mt][j], ah[mt], al[mt], bh, bl); }
    }
  }
  #pragma unroll
  for (int j = 0; j < 3; j++) {
    int n = (wv*3 + j)*16 + l15;
    int sl = n >> 7, col = n & 127;
    float* C = (sl == 0) ? C0 : (sl == 1) ? C1 : C2;
    float bb = b2[n];
    #pragma unroll
    for (int mt = 0; mt < 2; mt++)
      #pragma unroll
      for (int i = 0; i < 4; i++) {
        long row = r0 + mt*16 + q*4 + i;
        if (row < M) C[row*128 + col] = acc[mt][j][i] + bb;
      }
  }
  #undef XH_
  #undef XL_
  #undef TH_
  #undef TL_
}

// ---------------- FUSED message pass + Uv/Vv/Vn/s + a-MLP + update (muva, R26) ----------------
// R26 = R25 with the LAST-layer output head done via MFMA instead of scalar VALU:
//  - R25's head: 128 iters x (1 global + 2 scalar ds_read + 2 chained fma) per thread
//    ~ 640 inst, latency-bound at 3 blocks/CU -> ~85us. z = x@Wo1 is a 16x128 @ 128x64
//    matmul: waves 0-3 each compute one 16-col tile with 4xMFMA3 (GEMM1 pattern),
//    silu*Wo2 epilogue, 16-lane shfl_xor h-reduce, 4-way LDS combine, 16 atomics/block.
//  - Wo1 pre-split to transposed bf16 hi/lo (WOh/WOl) like every other weight.
template<int FIRST, int LAST>
__global__ void __launch_bounds__(512, 3) muva_kernel(
    const float* __restrict__ phi0, const float* __restrict__ phi1,
    const float* __restrict__ phi2, const float* __restrict__ vA,
    float* __restrict__ vB, float* __restrict__ x,
    const int* __restrict__ srcs, const float4* __restrict__ eg1,
    const float4* __restrict__ eg2, const int* __restrict__ indptr,
    const float* __restrict__ Wf_l, const float* __restrict__ bf_l,
    const short* __restrict__ Uth, const short* __restrict__ Utl,
    const short* __restrict__ Vth, const short* __restrict__ Vtl,
    const short* __restrict__ W1h, const short* __restrict__ W1l, const float* __restrict__ b1,
    const short* __restrict__ W2h, const short* __restrict__ W2l, const float* __restrict__ b2,
    const short* __restrict__ WOh, const short* __restrict__ WOl,
    const float* __restrict__ bo1,
    const float* __restrict__ Wo2, const float* __restrict__ bo2,
    const int* __restrict__ batch, float* __restrict__ out) {
  __shared__ float smem[8896];   // 35584 B
  // region A floats [0,6720): VN [48][140] fp32 deltas during sweep,
  //   then converted IN PLACE to shorts: VNH[48][136] @0 | VNL[48][136] @6528
  //   then overlaid by CATH[16][264] @0 | CATL @4224 | T2H[16][136] @8448 | T2L @10624
  //   LAST head overlay (all prior dead): XH2[16][136] @sms 0 | XL2 @sms 2176 |
  //     partials float[4][16] @smem 2200 (bytes 8800..9055, clear of shorts 0..4351)
  // region B floats [6720,8896): XN [16][136] fp32 (delta then full; intact until epilogue;
  //   on last layer holds FINAL x rows for the fused output head)
  short* sms = (short*)smem;
  #define VN(r,c)   smem[(r)*140 + (c)]
  #define XN(r,c)   smem[6720 + (r)*136 + (c)]
  #define VNH(r,c)  sms[(r)*136 + (c)]
  #define VNL(r,c)  sms[6528 + (r)*136 + (c)]
  #define CATH(r,c) sms[(r)*264 + (c)]
  #define CATL(r,c) sms[4224 + (r)*264 + (c)]
  #define T2H(r,c)  sms[8448 + (r)*136 + (c)]
  #define T2L(r,c)  sms[10624 + (r)*136 + (c)]
  const long NND = (long)NN*DD;
  int tid = threadIdx.x;
  long nb = (long)blockIdx.x * 16;
  // ---- phase E: edge sweep. 4 groups x 128 d-lanes; group g handles nodes 4g..4g+3 ----
  {
    int gs = __builtin_amdgcn_readfirstlane((int)(tid >> 7));   // wave-uniform group id
    int d  = tid & 127;
    float wf0[NB_], wf1[NB_], wf2[NB_];
    #pragma unroll
    for (int k = 0; k < NB_; k++) {
      wf0[k] = Wf_l[k*D3 + d];
      wf1[k] = Wf_l[k*D3 + DD + d];
      wf2[k] = Wf_l[k*D3 + 2*DD + d];
    }
    // pin: make each wf value an asm output -> not rematerializable (R18 behavior kept)
    #pragma unroll
    for (int k = 0; k < NB_; k++) {
      asm volatile("" : "+v"(wf0[k]), "+v"(wf1[k]), "+v"(wf2[k]));
    }
    float bf0 = bf_l[d], bf1 = bf_l[DD + d], bf2 = bf_l[2*DD + d];
    long n0g = nb + 4*gs;
    int b0  = __builtin_amdgcn_readfirstlane(indptr[n0g]);
    int b1_ = __builtin_amdgcn_readfirstlane(indptr[n0g+1]);
    int b2_ = __builtin_amdgcn_readfirstlane(indptr[n0g+2]);
    int b3_ = __builtin_amdgcn_readfirstlane(indptr[n0g+3]);
    int b4_ = __builtin_amdgcn_readfirstlane(indptr[n0g+4]);
    // pipeline state: slot A/B = {per-lane gathers, uniform geometry}; src ring 4 ahead
    int sA = 0, sB = 0;
    float p0A=0,p1A=0,p2A=0,w0A=0,w1A=0,w2A=0;
    float p0B=0,p1B=0,p2B=0,w0B=0,w1B=0,w2B=0;
    float4 g1A={}, g2A={}, g1B={}, g2B={};
    if (b0 < b4_) {
      int s0 = srcs[b0];
      long bb = (long)s0*DD + d;
      p0A = phi0[bb]; p1A = phi1[bb]; p2A = phi2[bb];
      if (!FIRST) { w0A = vA[bb]; w1A = vA[NND+bb]; w2A = vA[2*NND+bb]; }
      g1A = eg1[b0]; g2A = eg2[b0];
    }
    if (b0 + 1 < b4_) {
      int s1v = srcs[b0+1];
      long bb = (long)s1v*DD + d;
      p0B = phi0[bb]; p1B = phi1[bb]; p2B = phi2[bb];
      if (!FIRST) { w0B = vA[bb]; w1B = vA[NND+bb]; w2B = vA[2*NND+bb]; }
      g1B = eg1[b0+1]; g2B = eg2[b0+1];
    }
    if (b0 + 2 < b4_) sA = srcs[b0+2];
    if (b0 + 3 < b4_) sB = srcs[b0+3];
    float xacc=0.f, a0=0.f, a1=0.f, a2=0.f;
    int e = b0, cur = 0, nxt = b1_;
    // body: flush-check -> compute slot -> refill same slot for e+2 (no moves) -> src e+4
#define SW_BODY(P0,P1,P2,W0,W1,W2, G1, G2, SS) \
    { while (e >= nxt) { int nr = 4*gs + cur; \
        XN(nr, d) = xacc; VN(nr, d) = a0; VN(16+nr, d) = a1; VN(32+nr, d) = a2; \
        xacc = 0.f; a0 = 0.f; a1 = 0.f; a2 = 0.f; \
        cur++; nxt = (cur == 1) ? b2_ : (cur == 2) ? b3_ : b4_; } \
      float c2 = 2.0f * G1.y; \
      float rkm1 = 0.f, rk = G1.x, dot0 = 0.f, dot1 = 0.f, dot2 = 0.f; \
      _Pragma("unroll") \
      for (int k = 0; k < NB_; k++) { \
        dot0 = fmaf(rk, wf0[k], dot0); \
        dot1 = fmaf(rk, wf1[k], dot1); \
        dot2 = fmaf(rk, wf2[k], dot2); \
        float rn = fmaf(c2, rk, -rkm1); \
        rkm1 = rk; rk = rn; } \
      xacc = fmaf(P0, bf0*G1.z + G1.w*dot0, xacc); \
      float m1 = P1 * (bf1*G1.z + G1.w*dot1); \
      float m2 = P2 * (bf2*G1.z + G1.w*dot2); \
      a0 = fmaf(m1, G2.x, fmaf(m2, W0, a0)); \
      a1 = fmaf(m1, G2.y, fmaf(m2, W1, a1)); \
      a2 = fmaf(m1, G2.z, fmaf(m2, W2, a2)); \
      if (e + 2 < b4_) { \
        long bb = (long)SS*DD + d; \
        P0 = phi0[bb]; P1 = phi1[bb]; P2 = phi2[bb]; \
        if (!FIRST) { W0 = vA[bb]; W1 = vA[NND+bb]; W2 = vA[2*NND+bb]; } \
        G1 = eg1[e+2]; G2 = eg2[e+2]; } \
      if (e + 4 < b4_) SS = srcs[e+4]; \
      ++e; }
    while (e < b4_) {
      SW_BODY(p0A,p1A,p2A,w0A,w1A,w2A, g1A, g2A, sA)
      if (e >= b4_) break;
      SW_BODY(p0B,p1B,p2B,w0B,w1B,w2B, g1B, g2B, sB)
    }
#undef SW_BODY
    while (cur < 4) {
      int nr = 4*gs + cur;
      XN(nr, d) = xacc; VN(nr, d) = a0; VN(16+nr, d) = a1; VN(32+nr, d) = a2;
      xacc = 0.f; a0 = 0.f; a1 = 0.f; a2 = 0.f;
      cur++;
    }
  }
  // ---- issue base-row loads BEFORE the barrier (overlap with sweep stragglers) ----
  int lane = tid & 63, wv = tid >> 6;   // wv 0..7
  int l15 = lane & 15, q = lane >> 4;
  int dc = wv*16 + l15;                 // this wave's column slice
  float4 vb4[3]; float4 xb4;
  {
    int ch = tid * 3;                   // 1536 float4-chunks: 48 rows x 32
    #pragma unroll
    for (int j = 0; j < 3; j++) {
      if (!FIRST) {
        int r = (ch + j) >> 5, c4 = (ch + j) & 31;
        vb4[j] = *(const float4*)(vA + (long)(r >> 4)*NND + (nb + (r & 15))*DD + c4*4);
      } else {
        vb4[j] = make_float4(0.f, 0.f, 0.f, 0.f);
      }
    }
    int r = tid >> 5, c4 = tid & 31;
    xb4 = *(const float4*)(x + (nb + r)*DD + c4*4);
  }
  float vbold[4][3];
  #pragma unroll
  for (int i = 0; i < 4; i++)
    #pragma unroll
    for (int c = 0; c < 3; c++)
      vbold[i][c] = FIRST ? 0.f : vA[(long)c*NND + (nb + q*4 + i)*DD + dc];
  __syncthreads();
  // ---- capture v delta, add bases to VN chunks (regs) and XN (in place) ----
  float voldd[4][3];
  #pragma unroll
  for (int i = 0; i < 4; i++)
    #pragma unroll
    for (int c = 0; c < 3; c++) voldd[i][c] = VN(c*16 + q*4 + i, dc);
  float4 cf[3];
  {
    int ch = tid * 3;
    #pragma unroll
    for (int j = 0; j < 3; j++) {
      int r = (ch + j) >> 5, c4 = (ch + j) & 31;
      float4 t = *(const float4*)&VN(r, c4*4);
      cf[j] = make_float4(vb4[j].x + t.x, vb4[j].y + t.y, vb4[j].z + t.z, vb4[j].w + t.w);
    }
    int r = tid >> 5, c4 = tid & 31;
    float4 t = *(float4*)&XN(r, c4*4);
    *(float4*)&XN(r, c4*4) = make_float4(xb4.x + t.x, xb4.y + t.y, xb4.z + t.z, xb4.w + t.w);
  }
  __syncthreads();                      // all fp32 reads done before short overwrite
  {
    int ch = tid * 3;
    #pragma unroll
    for (int j = 0; j < 3; j++) {
      int r = (ch + j) >> 5, c4 = (ch + j) & 31;
      split_store4(cf[j], &VNH(r, c4*4), &VNL(r, c4*4));
    }
  }
  __syncthreads();
  // ---- phase 1: U & V projections for column-slice dc (A-fragments pre-split) ----
  v4f aU[3] = {}, aV[3] = {};
  #pragma unroll
  for (int s = 0; s < 4; s++) {
    long boff = (long)dc*128 + s*32 + q*8;
    v8s buh = *(const v8s*)(Uth + boff);
    v8s bul = *(const v8s*)(Utl + boff);
    v8s bvh = *(const v8s*)(Vth + boff);
    v8s bvl = *(const v8s*)(Vtl + boff);
    #pragma unroll
    for (int c = 0; c < 3; c++) {
      v8s ah = *(const v8s*)&VNH(c*16 + l15, s*32 + q*8);
      v8s al = *(const v8s*)&VNL(c*16 + l15, s*32 + q*8);
      MFMA3(aU[c], ah, al, buh, bul);
      MFMA3(aV[c], ah, al, bvh, bvl);
    }
  }
  float sreg[4], vn2[4];
  #pragma unroll
  for (int i = 0; i < 4; i++) {
    sreg[i] = aU[0][i]*aV[0][i] + aU[1][i]*aV[1][i] + aU[2][i]*aV[2][i];
    vn2[i]  = aV[0][i]*aV[0][i] + aV[1][i]*aV[1][i] + aV[2][i]*aV[2][i];
  }
  __syncthreads();   // all reads of VNH/VNL complete before CAT overlay
  // ---- build cat = [x_new | Vn] directly as bf16 hi/lo (split once by producer) ----
  {
    int r = tid >> 5, c4 = tid & 31;   // 512 tasks: 16 rows x 32 float4-chunks
    float4 f = *(const float4*)&XN(r, c4*4);
    split_store4(f, &CATH(r, c4*4), &CATL(r, c4*4));
  }
  #pragma unroll
  for (int i = 0; i < 4; i++) {
    short h, l;
    split2(sqrtf(vn2[i] + 1e-8f), h, l);
    CATH(q*4 + i, 128 + dc) = h;
    CATL(q*4 + i, 128 + dc) = l;
  }
  __syncthreads();
  // ---- GEMM1: t2[:, dc] = silu(cat @ Wu1 + b1), K=256; t2 written pre-split ----
  {
    v4f acc = {};
    #pragma unroll
    for (int s = 0; s < 8; s++) {
      v8s ah = *(const v8s*)&CATH(l15, s*32 + q*8);
      v8s al = *(const v8s*)&CATL(l15, s*32 + q*8);
      v8s bh = *(const v8s*)(W1h + (long)dc*256 + s*32 + q*8);
      v8s bl = *(const v8s*)(W1l + (long)dc*256 + s*32 + q*8);
      MFMA3(acc, ah, al, bh, bl);
    }
    float bb = b1[dc];
    #pragma unroll
    for (int i = 0; i < 4; i++) {
      short h, l;
      split2(silu_f(acc[i] + bb), h, l);
      T2H(q*4 + i, dc) = h;
      T2L(q*4 + i, dc) = l;
    }
  }
  __syncthreads();
  // ---- GEMM2 + epilogue ----
  {
    v4f acc[3] = {};
    #pragma unroll
    for (int s = 0; s < 4; s++) {
      v8s ah = *(const v8s*)&T2H(l15, s*32 + q*8);
      v8s al = *(const v8s*)&T2L(l15, s*32 + q*8);
      #pragma unroll
      for (int g = 0; g < 3; g++) {
        int n = g*128 + dc;                 // avv: dc, asv: 128+dc, ass: 256+dc
        v8s bh = *(const v8s*)(W2h + (long)n*128 + s*32 + q*8);
        v8s bl = *(const v8s*)(W2l + (long)n*128 + s*32 + q*8);
        MFMA3(acc[g], ah, al, bh, bl);
      }
    }
    float bavv = b2[dc], basv = b2[128 + dc], bass = b2[256 + dc];
    #pragma unroll
    for (int i = 0; i < 4; i++) {
      int lr = q*4 + i;
      long row = nb + lr;
      float avv = acc[0][i] + bavv;
      float asv = acc[1][i] + basv;
      float ass = acc[2][i] + bass;
      float xf = XN(lr, dc) + ass + asv * sreg[i];
      if (!LAST) {
        x[row*DD + dc] = xf;
        #pragma unroll
        for (int c = 0; c < 3; c++)
          vB[(long)c*NND + row*DD + dc] = fmaf(avv, aU[c][i], voldd[i][c] + vbold[i][c]);
      } else {
        XN(lr, dc) = xf;    // keep final x row in LDS for the fused head
      }
    }
  }
  // ---- fused output head (LAST only): out += silu(x@Wo1+bo1)@Wo2 + bo2 via MFMA ----
  if (LAST) {
    __syncthreads();        // all final XN writes visible
    // split final x rows to bf16 hi/lo: XH2 @sms 0, XL2 @sms 2176 (regions dead)
    {
      int r = tid >> 5, c4 = tid & 31;
      float4 f = *(const float4*)&XN(r, c4*4);
      split_store4(f, &sms[r*136 + c4*4], &sms[2176 + r*136 + c4*4]);
    }
    __syncthreads();
    // z[16][64] = x @ Wo1: waves 0-3 each own n-tile wv (h = wv*16 + l15)
    if (wv < 4) {
      int n = wv*16 + l15;
      v4f accz = {};
      #pragma unroll
      for (int s = 0; s < 4; s++) {
        v8s ah = *(const v8s*)&sms[l15*136 + s*32 + q*8];
        v8s al = *(const v8s*)&sms[2176 + l15*136 + s*32 + q*8];
        v8s bh = *(const v8s*)(WOh + (long)n*128 + s*32 + q*8);
        v8s bl = *(const v8s*)(WOl + (long)n*128 + s*32 + q*8);
        MFMA3(accz, ah, al, bh, bl);
      }
      float bo1v = bo1[n], wo2v = Wo2[n];
      #pragma unroll
      for (int i = 0; i < 4; i++) {
        float val = silu_f(accz[i] + bo1v) * wo2v;   // z[q*4+i][n]
        #pragma unroll
        for (int off = 1; off < 16; off <<= 1) val += __shfl_xor(val, off, 16);
        if (l15 == 0) smem[2200 + wv*16 + q*4 + i] = val;   // partial per (tile, row)
      }
    }
    __syncthreads();
    if (tid < 16) {
      float s_ = smem[2200 + tid] + smem[2200 + 16 + tid]
               + smem[2200 + 32 + tid] + smem[2200 + 48 + tid];
      atomicAdd(&out[batch[nb + tid]], s_ + bo2[0]);
    }
  }
  #undef VN
  #undef XN
  #undef VNH
  #undef VNL
  #undef CATH
  #undef CATL
  #undef T2H
  #undef T2L
}

// ---------------- launcher ----------------
extern "C" void kernel_launch(void* const* d_in, const int* in_sizes, int n_in,
                              void* d_out, int out_size, void* d_ws, size_t ws_size,
                              hipStream_t stream) {
  const int*   at_no = (const int*)d_in[0];
  const float* pos   = (const float*)d_in[1];
  const int*   ei    = (const int*)d_in[2];
  const int*   batch = (const int*)d_in[3];
  const float* emb   = (const float*)d_in[4];
  const float* Wf    = (const float*)d_in[5];
  const float* bfp   = (const float*)d_in[6];
  const float* Wm1   = (const float*)d_in[7];
  const float* bm1   = (const float*)d_in[8];
  const float* Wm2   = (const float*)d_in[9];
  const float* bm2   = (const float*)d_in[10];
  const float* U     = (const float*)d_in[11];
  const float* V     = (const float*)d_in[12];
  const float* Wu1   = (const float*)d_in[13];
  const float* bu1   = (const float*)d_in[14];
  const float* Wu2   = (const float*)d_in[15];
  const float* bu2   = (const float*)d_in[16];
  const float* Wo1   = (const float*)d_in[17];
  const float* bo1   = (const float*)d_in[18];
  const float* Wo2   = (const float*)d_in[19];
  const float* bo2   = (const float*)d_in[20];
  float* out = (float*)d_out;

  char* w = (char*)d_ws;
  auto alloc = [&](size_t bytes) -> void* {
    void* p = (void*)w;
    w += (bytes + 255) & ~(size_t)255;
    return p;
  };
  float*  x      = (float*)alloc(sizeof(float)*(size_t)NN*DD);
  float*  v_a    = (float*)alloc(sizeof(float)*(size_t)NN*D3);   // plane layout [3][NN][DD]
  float*  v_b    = (float*)alloc(sizeof(float)*(size_t)NN*D3);
  float*  t1     = (float*)alloc(sizeof(float)*(size_t)NN*DD);   // phi slice 2
  float*  phiS   = (float*)alloc(sizeof(float)*(size_t)NN*DD);   // phi slice 1
  float*  phi0   = (float*)alloc(sizeof(float)*(size_t)NN*DD);   // phi slice 0
  short*  wbh    = (short*)alloc(sizeof(short)*(size_t)3*LSZ);   // bf16-hi weights
  short*  wbl    = (short*)alloc(sizeof(short)*(size_t)3*LSZ);   // bf16-lo weights
  short*  woh    = (short*)alloc(sizeof(short)*(size_t)HH*DD);   // Wo1 bf16-hi [64][128]
  short*  wol    = (short*)alloc(sizeof(short)*(size_t)HH*DD);   // Wo1 bf16-lo
  int*    srcs   = (int*)alloc(sizeof(int)*(size_t)ECAP);
  float4* eg1    = (float4*)alloc(sizeof(float4)*(size_t)ECAP);
  float4* eg2    = (float4*)alloc(sizeof(float4)*(size_t)ECAP);
  int*    indptr = (int*)alloc(sizeof(int)*((size_t)NN+1));
  int*    counts = (int*)alloc(sizeof(int)*(size_t)NN);

  if ((size_t)(w - (char*)d_ws) > ws_size) {   // diagnostic guard: zeros => ws too small
    zero_f_kernel<<<2, 256, 0, stream>>>(out, NG_);
    return;
  }

  // NOTE: v_a zero-fill not needed — layer 0 runs FIRST=1 and never reads vA.
  zero_f_kernel<<<2, 256, 0, stream>>>(out, NG_);
  zero_i_kernel<<<64, 256, 0, stream>>>(counts, NN);
  init_x_kernel<<<(NN*DD + 255)/256, 256, 0, stream>>>(at_no, emb, x);
  prep_w_kernel<<<(3*LSZ + 255)/256, 256, 0, stream>>>(Wm1, Wm2, U, V, Wu1, Wu2, wbh, wbl);
  prep_wo_kernel<<<(HH*DD + 255)/256, 256, 0, stream>>>(Wo1, woh, wol);
  hist_kernel<<<(NE + 255)/256, 256, 0, stream>>>(ei, pos, counts);
  scan_kernel<<<1, 1024, 0, stream>>>(counts, indptr, NN);
  zero_i_kernel<<<64, 256, 0, stream>>>(counts, NN);
  fill_kernel<<<(NE + 255)/256, 256, 0, stream>>>(ei, pos, indptr, counts, srcs, eg1, eg2);

  const int MB = (NN + 31) / 32;    // 1563
  float* vcur = v_a;
  float* vnext = v_b;
  for (int l = 0; l < 3; l++) {
    const float* Wf_l  = Wf  + (size_t)l*NB_*D3;
    const float* bf_l  = bfp + (size_t)l*D3;
    const float* bm1_l = bm1 + (size_t)l*DD;
    const float* bm2_l = bm2 + (size_t)l*D3;
    const float* bu1_l = bu1 + (size_t)l*DD;
    const float* bu2_l = bu2 + (size_t)l*D3;
    const short* Lh = wbh + (size_t)l*LSZ;
    const short* Ll = wbl + (size_t)l*LSZ;
    const short* Wm1h = Lh,          *Wm1L = Ll;
    const short* Wm2h = Lh + 16384,  *Wm2L = Ll + 16384;
    const short* Uh   = Lh + 65536,  *UL   = Ll + 65536;
    const short* Vh   = Lh + 81920,  *VL   = Ll + 81920;
    const short* Wu1h = Lh + 98304,  *Wu1L = Ll + 98304;
    const short* Wu2h = Lh + 131072, *Wu2L = Ll + 131072;

    // fused node-MLP: x -> t2 (LDS) -> phi slices {phi0, phiS, t1}
    mlp_phi_kernel<<<MB, 512, 0, stream>>>(x, Wm1h, Wm1L, bm1_l, Wm2h, Wm2L, bm2_l,
                                           phi0, phiS, t1, NN);
    // fused: edge sweep + U/V proj + a-MLP + x,v update; templated per layer
    if (l == 0) {
      muva_kernel<1,0><<<NN/16, 512, 0, stream>>>(phi0, phiS, t1, vcur, vnext, x,
                                                  srcs, eg1, eg2, indptr, Wf_l, bf_l,
                                                  Uh, UL, Vh, VL,
                                                  Wu1h, Wu1L, bu1_l, Wu2h, Wu2L, bu2_l,
                                                  woh, wol, bo1, Wo2, bo2, batch, out);
    } else if (l == 1) {
      muva_kernel<0,0><<<NN/16, 512, 0, stream>>>(phi0, phiS, t1, vcur, vnext, x,
                                                  srcs, eg1, eg2, indptr, Wf_l, bf_l,
                                                  Uh, UL, Vh, VL,
                                                  Wu1h, Wu1L, bu1_l, Wu2h, Wu2L, bu2_l,
                                                  woh, wol, bo1, Wo2, bo2, batch, out);
    } else {
      muva_kernel<0,1><<<NN/16, 512, 0, stream>>>(phi0, phiS, t1, vcur, vnext, x,
                                                  srcs, eg1, eg2, indptr, Wf_l, bf_l,
                                                  Uh, UL, Vh, VL,
                                                  Wu1h, Wu1L, bu1_l, Wu2h, Wu2L, bu2_l,
                                                  woh, wol, bo1, Wo2, bo2, batch, out);
    }

    float* tmp = vcur; vcur = vnext; vnext = tmp;
  }

  (void)in_sizes; (void)n_in; (void)out_size; (void)ws_size;
}

// Round 14
// 1240.327 us; speedup vs baseline: 1.1144x; 1.0073x over previous
//
#include <hip/hip_runtime.h>
#include <math.h>

#define NN 50000
#define NE 600000
#define ECAP 230000  // capacity for filtered edges (actual ~175K)
#define DD 128
#define D3 384
#define NB_ 20
#define HH 64
#define NG_ 512
#define LSZ 180224   // shorts per layer of transposed-bf16 weights

typedef short v8s __attribute__((ext_vector_type(8)));
typedef short v4sh __attribute__((ext_vector_type(4)));
typedef float v4f __attribute__((ext_vector_type(4)));

__device__ __forceinline__ float silu_f(float z) { return z / (1.0f + expf(-z)); }

__device__ __forceinline__ short f2bf(float f) {
  unsigned u = __float_as_uint(f);
  u += 0x7FFF + ((u >> 16) & 1);          // RNE
  return (short)(u >> 16);
}
__device__ __forceinline__ float bf2f(short s) {
  return __uint_as_float(((unsigned)(unsigned short)s) << 16);
}
__device__ __forceinline__ void split2(float x, short& h, short& l) {
  h = f2bf(x);
  l = f2bf(x - bf2f(h));
}
// split a float4 and store hi/lo as short4 (8B LDS stores)
__device__ __forceinline__ void split_store4(float4 f, short* hp, short* lp) {
  short h0,l0,h1,l1,h2,l2,h3,l3;
  split2(f.x,h0,l0); split2(f.y,h1,l1); split2(f.z,h2,l2); split2(f.w,h3,l3);
  v4sh hv = {h0,h1,h2,h3}, lv = {l0,l1,l2,l3};
  *(v4sh*)hp = hv; *(v4sh*)lp = lv;
}
// 3-term Markidis split: acc += ah@bh + al@bh + ah@bl   (proven: absmax 4.3e9)
#define MFMA3(acc, ah, al, bh, bl) \
  acc = __builtin_amdgcn_mfma_f32_16x16x32_bf16(ah, bh, acc, 0, 0, 0); \
  acc = __builtin_amdgcn_mfma_f32_16x16x32_bf16(al, bh, acc, 0, 0, 0); \
  acc = __builtin_amdgcn_mfma_f32_16x16x32_bf16(ah, bl, acc, 0, 0, 0);

// ---------------- utility ----------------
__global__ void zero_f_kernel(float* __restrict__ p, long n) {
  long i = (long)blockIdx.x * blockDim.x + threadIdx.x;
  long s = (long)gridDim.x * blockDim.x;
  for (; i < n; i += s) p[i] = 0.0f;
}

__global__ void zero_i_kernel(int* __restrict__ p, long n) {
  long i = (long)blockIdx.x * blockDim.x + threadIdx.x;
  long s = (long)gridDim.x * blockDim.x;
  for (; i < n; i += s) p[i] = 0;
}

__global__ void init_x_kernel(const int* __restrict__ at_no, const float* __restrict__ emb,
                              float* __restrict__ x) {
  int i = blockIdx.x * blockDim.x + threadIdx.x;
  if (i >= NN * DD) return;
  x[i] = emb[at_no[i >> 7] * DD + (i & 127)];
}

// ---------------- weight prep: fp32 [K][N] -> transposed bf16 hi/lo [N][K] ----------------
__global__ void prep_w_kernel(const float* __restrict__ Wm1, const float* __restrict__ Wm2,
                              const float* __restrict__ U, const float* __restrict__ V,
                              const float* __restrict__ Wu1, const float* __restrict__ Wu2,
                              short* __restrict__ hi, short* __restrict__ lo) {
  int idx = blockIdx.x * 256 + threadIdx.x;
  if (idx >= 3 * LSZ) return;
  int l = idx / LSZ, r = idx % LSZ;
  const float* src; int K, N, nk;
  if (r < 16384)       { src = Wm1 + (size_t)l*16384; K = 128; N = 128; nk = r; }
  else if (r < 65536)  { src = Wm2 + (size_t)l*49152; K = 128; N = 384; nk = r - 16384; }
  else if (r < 81920)  { src = U   + (size_t)l*16384; K = 128; N = 128; nk = r - 65536; }
  else if (r < 98304)  { src = V   + (size_t)l*16384; K = 128; N = 128; nk = r - 81920; }
  else if (r < 131072) { src = Wu1 + (size_t)l*32768; K = 256; N = 128; nk = r - 98304; }
  else                 { src = Wu2 + (size_t)l*49152; K = 128; N = 384; nk = r - 131072; }
  int n = nk / K, k = nk - n * K;
  float xx = src[(size_t)k * N + n];
  short h = f2bf(xx);
  hi[idx] = h;
  lo[idx] = f2bf(xx - bf2f(h));
}

// Wo1 prep: fp32 [DD][HH] -> transposed bf16 hi/lo [HH][DD] (same layout as other weights)
__global__ void prep_wo_kernel(const float* __restrict__ Wo1,
                               short* __restrict__ hi, short* __restrict__ lo) {
  int idx = blockIdx.x * 256 + threadIdx.x;
  if (idx >= HH * DD) return;
  int n = idx >> 7, k = idx & 127;
  float xx = Wo1[(size_t)k * HH + n];
  short h = f2bf(xx);
  hi[idx] = h;
  lo[idx] = f2bf(xx - bf2f(h));
}

// ---------------- CSR build (dst-sorted), filtering dist>=CUTOFF edges ----------------
__global__ void hist_kernel(const int* __restrict__ ei, const float* __restrict__ pos,
                            int* __restrict__ counts) {
  int e = blockIdx.x * blockDim.x + threadIdx.x;
  if (e >= NE) return;
  int s = ei[e], d = ei[NE + e];
  float dx = pos[3*d]   - pos[3*s];
  float dy = pos[3*d+1] - pos[3*s+1];
  float dz = pos[3*d+2] - pos[3*s+2];
  float d2 = dx*dx + dy*dy + dz*dz + 1e-12f;
  if (d2 < 25.0f) atomicAdd(&counts[d], 1);
}

__global__ void scan_kernel(const int* __restrict__ counts, int* __restrict__ indptr, int n) {
  __shared__ int sm[1024];
  __shared__ int carry_s;
  if (threadIdx.x == 0) carry_s = 0;
  __syncthreads();
  for (int start = 0; start < n; start += 1024) {
    int i = start + (int)threadIdx.x;
    int val = (i < n) ? counts[i] : 0;
    sm[threadIdx.x] = val;
    __syncthreads();
    for (int off = 1; off < 1024; off <<= 1) {
      int t = (threadIdx.x >= (unsigned)off) ? sm[threadIdx.x - off] : 0;
      __syncthreads();
      sm[threadIdx.x] += t;
      __syncthreads();
    }
    int c = carry_s;
    if (i < n) indptr[i] = c + sm[threadIdx.x] - val;
    __syncthreads();
    if (threadIdx.x == 0) carry_s = c + sm[1023];
    __syncthreads();
  }
  if (threadIdx.x == 0) indptr[n] = carry_s;
}

__global__ void fill_kernel(const int* __restrict__ ei, const float* __restrict__ pos,
                            const int* __restrict__ indptr, int* __restrict__ cursor,
                            int* __restrict__ srcs, float4* __restrict__ eg1,
                            float4* __restrict__ eg2) {
  int e = blockIdx.x * blockDim.x + threadIdx.x;
  if (e >= NE) return;
  int s = ei[e], d = ei[NE + e];
  float dx = pos[3*d]   - pos[3*s];
  float dy = pos[3*d+1] - pos[3*s+1];
  float dz = pos[3*d+2] - pos[3*s+2];
  float d2 = dx*dx + dy*dy + dz*dz + 1e-12f;
  if (d2 < 25.0f) {
    int p = atomicAdd(&cursor[d], 1);
    int slot = indptr[d] + p;
    float dist = sqrtf(d2);
    float inv = 1.0f / dist;
    float wang = 0.62831853071795864769f * dist;   // pi*dist/CUTOFF
    float s1 = __sinf(wang), c1 = __cosf(wang);
    float fc = 0.5f * (c1 + 1.0f);
    srcs[slot] = s;
    eg1[slot] = make_float4(s1, c1, fc, fc * inv);
    eg2[slot] = make_float4(dx * inv, dy * inv, dz * inv, 0.0f);
  }
}

// ---------------- fused node MLP: phi = silu(x@Wm1+b1)@Wm2+b2 ----------------
// R27: phi emitted INTERLEAVED [NN][3][DD] (single buffer, C[row*384+n]) so the sweep's
// per-edge phi gather is one contiguous 1536B span (one DRAM page) instead of 3 planes
// 25MB apart. Row-local chain; t2 never leaves LDS. 512 thr / 8 waves, 32 rows/block.
__global__ void __launch_bounds__(512) mlp_phi_kernel(
    const float* __restrict__ x,
    const short* __restrict__ W1h, const short* __restrict__ W1l, const float* __restrict__ b1,
    const short* __restrict__ W2h, const short* __restrict__ W2l, const float* __restrict__ b2,
    float* __restrict__ C, int M) {
  __shared__ short sm[4 * 32 * 136];   // XH | XL | TH | TL
  #define XH_(r,c) sm[(r)*136 + (c)]
  #define XL_(r,c) sm[4352 + (r)*136 + (c)]
  #define TH_(r,c) sm[8704 + (r)*136 + (c)]
  #define TL_(r,c) sm[13056 + (r)*136 + (c)]
  int tid = threadIdx.x;
  long r0 = (long)blockIdx.x * 32;
  #pragma unroll
  for (int i = 0; i < 2; i++) {
    int lin = i*512 + tid;
    int r = lin >> 5, c4 = lin & 31;
    long row = r0 + r; if (row >= M) row = M - 1;
    float4 f = *(const float4*)(x + row*128 + c4*4);
    split_store4(f, &XH_(r, c4*4), &XL_(r, c4*4));
  }
  __syncthreads();
  int lane = tid & 63, wv = tid >> 6;   // wv 0..7
  int l15 = lane & 15, q = lane >> 4;
  // GEMM1: t2 = silu(x@Wm1 + b1); wave w owns cols w*16+l15
  {
    int n = wv*16 + l15;
    v4f acc[2] = {};
    #pragma unroll
    for (int s = 0; s < 4; s++) {
      v8s bh = *(const v8s*)(W1h + (long)n*128 + s*32 + q*8);
      v8s bl = *(const v8s*)(W1l + (long)n*128 + s*32 + q*8);
      #pragma unroll
      for (int mt = 0; mt < 2; mt++) {
        v8s ah = *(const v8s*)&XH_(mt*16 + l15, s*32 + q*8);
        v8s al = *(const v8s*)&XL_(mt*16 + l15, s*32 + q*8);
        MFMA3(acc[mt], ah, al, bh, bl);
      }
    }
    float bb = b1[n];
    #pragma unroll
    for (int mt = 0; mt < 2; mt++)
      #pragma unroll
      for (int i = 0; i < 4; i++) {
        short h, l;
        split2(silu_f(acc[mt][i] + bb), h, l);
        TH_(mt*16 + q*4 + i, n) = h;
        TL_(mt*16 + q*4 + i, n) = l;
      }
  }
  __syncthreads();
  // GEMM2: phi = t2@Wm2 + b2 (384 cols; wave w -> n-tiles w*3..w*3+2)
  v4f acc[2][3] = {};
  #pragma unroll
  for (int s = 0; s < 4; s++) {
    v8s ah[2], al[2];
    #pragma unroll
    for (int mt = 0; mt < 2; mt++) {
      ah[mt] = *(const v8s*)&TH_(mt*16 + l15, s*32 + q*8);
      al[mt] = *(const v8s*)&TL_(mt*16 + l15, s*32 + q*8);
    }
    #pragma unroll
    for (int j = 0; j < 3; j++) {
      int n = (wv*3 + j)*16 + l15;
      v8s bh = *(const v8s*)(W2h + (long)n*128 + s*32 + q*8);
      v8s bl = *(const v8s*)(W2l + (long)n*128 + s*32 + q*8);
      #pragma unroll
      for (int mt = 0; mt < 2; mt++) { MFMA3(acc[mt][j], ah[mt], al[mt], bh, bl); }
    }
  }
  #pragma unroll
  for (int j = 0; j < 3; j++) {
    int n = (wv*3 + j)*16 + l15;
    float bb = b2[n];
    #pragma unroll
    for (int mt = 0; mt < 2; mt++)
      #pragma unroll
      for (int i = 0; i < 4; i++) {
        long row = r0 + mt*16 + q*4 + i;
        if (row < M) C[row*D3 + n] = acc[mt][j][i] + bb;
      }
  }
  #undef XH_
  #undef XL_
  #undef TH_
  #undef TL_
}

// ---------------- FUSED message pass + Uv/Vv/Vn/s + a-MLP + update (muva, R27) ----------------
// R27 = R26 with phi AND v in per-node interleaved layout [NN][3][DD]:
//  - per edge the 6 gathered scalars live in TWO contiguous 1536B spans (phi row, v row)
//    instead of SIX 512B rows 25MB apart -> 3x fewer DRAM page activations, and the
//    +128/+256 plane offsets fold into load-immediate offsets (512B/1024B < 13-bit).
//  - numerics bit-identical (pure index permutation).
template<int FIRST, int LAST>
__global__ void __launch_bounds__(512, 3) muva_kernel(
    const float* __restrict__ phi, const float* __restrict__ vA,
    float* __restrict__ vB, float* __restrict__ x,
    const int* __restrict__ srcs, const float4* __restrict__ eg1,
    const float4* __restrict__ eg2, const int* __restrict__ indptr,
    const float* __restrict__ Wf_l, const float* __restrict__ bf_l,
    const short* __restrict__ Uth, const short* __restrict__ Utl,
    const short* __restrict__ Vth, const short* __restrict__ Vtl,
    const short* __restrict__ W1h, const short* __restrict__ W1l, const float* __restrict__ b1,
    const short* __restrict__ W2h, const short* __restrict__ W2l, const float* __restrict__ b2,
    const short* __restrict__ WOh, const short* __restrict__ WOl,
    const float* __restrict__ bo1,
    const float* __restrict__ Wo2, const float* __restrict__ bo2,
    const int* __restrict__ batch, float* __restrict__ out) {
  __shared__ float smem[8896];   // 35584 B
  // region A floats [0,6720): VN [48][140] fp32 deltas during sweep,
  //   then converted IN PLACE to shorts: VNH[48][136] @0 | VNL[48][136] @6528
  //   then overlaid by CATH[16][264] @0 | CATL @4224 | T2H[16][136] @8448 | T2L @10624
  //   LAST head overlay (all prior dead): XH2[16][136] @sms 0 | XL2 @sms 2176 |
  //     partials float[4][16] @smem 2200
  // region B floats [6720,8896): XN [16][136] fp32 (delta then full; intact until epilogue;
  //   on last layer holds FINAL x rows for the fused output head)
  short* sms = (short*)smem;
  #define VN(r,c)   smem[(r)*140 + (c)]
  #define XN(r,c)   smem[6720 + (r)*136 + (c)]
  #define VNH(r,c)  sms[(r)*136 + (c)]
  #define VNL(r,c)  sms[6528 + (r)*136 + (c)]
  #define CATH(r,c) sms[(r)*264 + (c)]
  #define CATL(r,c) sms[4224 + (r)*264 + (c)]
  #define T2H(r,c)  sms[8448 + (r)*136 + (c)]
  #define T2L(r,c)  sms[10624 + (r)*136 + (c)]
  int tid = threadIdx.x;
  long nb = (long)blockIdx.x * 16;
  // ---- phase E: edge sweep. 4 groups x 128 d-lanes; group g handles nodes 4g..4g+3 ----
  {
    int gs = __builtin_amdgcn_readfirstlane((int)(tid >> 7));   // wave-uniform group id
    int d  = tid & 127;
    float wf0[NB_], wf1[NB_], wf2[NB_];
    #pragma unroll
    for (int k = 0; k < NB_; k++) {
      wf0[k] = Wf_l[k*D3 + d];
      wf1[k] = Wf_l[k*D3 + DD + d];
      wf2[k] = Wf_l[k*D3 + 2*DD + d];
    }
    // pin: make each wf value an asm output -> not rematerializable (R18 behavior kept)
    #pragma unroll
    for (int k = 0; k < NB_; k++) {
      asm volatile("" : "+v"(wf0[k]), "+v"(wf1[k]), "+v"(wf2[k]));
    }
    float bf0 = bf_l[d], bf1 = bf_l[DD + d], bf2 = bf_l[2*DD + d];
    long n0g = nb + 4*gs;
    int b0  = __builtin_amdgcn_readfirstlane(indptr[n0g]);
    int b1_ = __builtin_amdgcn_readfirstlane(indptr[n0g+1]);
    int b2_ = __builtin_amdgcn_readfirstlane(indptr[n0g+2]);
    int b3_ = __builtin_amdgcn_readfirstlane(indptr[n0g+3]);
    int b4_ = __builtin_amdgcn_readfirstlane(indptr[n0g+4]);
    // pipeline state: slot A/B = {per-lane gathers, uniform geometry}; src ring 4 ahead
    int sA = 0, sB = 0;
    float p0A=0,p1A=0,p2A=0,w0A=0,w1A=0,w2A=0;
    float p0B=0,p1B=0,p2B=0,w0B=0,w1B=0,w2B=0;
    float4 g1A={}, g2A={}, g1B={}, g2B={};
    if (b0 < b4_) {
      int s0 = srcs[b0];
      long bb = (long)s0*D3 + d;
      p0A = phi[bb]; p1A = phi[bb+DD]; p2A = phi[bb+2*DD];
      if (!FIRST) { w0A = vA[bb]; w1A = vA[bb+DD]; w2A = vA[bb+2*DD]; }
      g1A = eg1[b0]; g2A = eg2[b0];
    }
    if (b0 + 1 < b4_) {
      int s1v = srcs[b0+1];
      long bb = (long)s1v*D3 + d;
      p0B = phi[bb]; p1B = phi[bb+DD]; p2B = phi[bb+2*DD];
      if (!FIRST) { w0B = vA[bb]; w1B = vA[bb+DD]; w2B = vA[bb+2*DD]; }
      g1B = eg1[b0+1]; g2B = eg2[b0+1];
    }
    if (b0 + 2 < b4_) sA = srcs[b0+2];
    if (b0 + 3 < b4_) sB = srcs[b0+3];
    float xacc=0.f, a0=0.f, a1=0.f, a2=0.f;
    int e = b0, cur = 0, nxt = b1_;
    // body: flush-check -> compute slot -> refill same slot for e+2 (no moves) -> src e+4
#define SW_BODY(P0,P1,P2,W0,W1,W2, G1, G2, SS) \
    { while (e >= nxt) { int nr = 4*gs + cur; \
        XN(nr, d) = xacc; VN(nr, d) = a0; VN(16+nr, d) = a1; VN(32+nr, d) = a2; \
        xacc = 0.f; a0 = 0.f; a1 = 0.f; a2 = 0.f; \
        cur++; nxt = (cur == 1) ? b2_ : (cur == 2) ? b3_ : b4_; } \
      float c2 = 2.0f * G1.y; \
      float rkm1 = 0.f, rk = G1.x, dot0 = 0.f, dot1 = 0.f, dot2 = 0.f; \
      _Pragma("unroll") \
      for (int k = 0; k < NB_; k++) { \
        dot0 = fmaf(rk, wf0[k], dot0); \
        dot1 = fmaf(rk, wf1[k], dot1); \
        dot2 = fmaf(rk, wf2[k], dot2); \
        float rn = fmaf(c2, rk, -rkm1); \
        rkm1 = rk; rk = rn; } \
      xacc = fmaf(P0, bf0*G1.z + G1.w*dot0, xacc); \
      float m1 = P1 * (bf1*G1.z + G1.w*dot1); \
      float m2 = P2 * (bf2*G1.z + G1.w*dot2); \
      a0 = fmaf(m1, G2.x, fmaf(m2, W0, a0)); \
      a1 = fmaf(m1, G2.y, fmaf(m2, W1, a1)); \
      a2 = fmaf(m1, G2.z, fmaf(m2, W2, a2)); \
      if (e + 2 < b4_) { \
        long bb = (long)SS*D3 + d; \
        P0 = phi[bb]; P1 = phi[bb+DD]; P2 = phi[bb+2*DD]; \
        if (!FIRST) { W0 = vA[bb]; W1 = vA[bb+DD]; W2 = vA[bb+2*DD]; } \
        G1 = eg1[e+2]; G2 = eg2[e+2]; } \
      if (e + 4 < b4_) SS = srcs[e+4]; \
      ++e; }
    while (e < b4_) {
      SW_BODY(p0A,p1A,p2A,w0A,w1A,w2A, g1A, g2A, sA)
      if (e >= b4_) break;
      SW_BODY(p0B,p1B,p2B,w0B,w1B,w2B, g1B, g2B, sB)
    }
#undef SW_BODY
    while (cur < 4) {
      int nr = 4*gs + cur;
      XN(nr, d) = xacc; VN(nr, d) = a0; VN(16+nr, d) = a1; VN(32+nr, d) = a2;
      xacc = 0.f; a0 = 0.f; a1 = 0.f; a2 = 0.f;
      cur++;
    }
  }
  // ---- issue base-row loads BEFORE the barrier (overlap with sweep stragglers) ----
  int lane = tid & 63, wv = tid >> 6;   // wv 0..7
  int l15 = lane & 15, q = lane >> 4;
  int dc = wv*16 + l15;                 // this wave's column slice
  float4 vb4[3]; float4 xb4;
  {
    int ch = tid * 3;                   // 1536 float4-chunks: 48 rows x 32
    #pragma unroll
    for (int j = 0; j < 3; j++) {
      if (!FIRST) {
        int r = (ch + j) >> 5, c4 = (ch + j) & 31;
        // VN row r = (plane r>>4, node r&15); vA interleaved [NN][3][DD]
        vb4[j] = *(const float4*)(vA + (nb + (r & 15))*D3 + (r >> 4)*DD + c4*4);
      } else {
        vb4[j] = make_float4(0.f, 0.f, 0.f, 0.f);
      }
    }
    int r = tid >> 5, c4 = tid & 31;
    xb4 = *(const float4*)(x + (nb + r)*DD + c4*4);
  }
  float vbold[4][3];
  #pragma unroll
  for (int i = 0; i < 4; i++)
    #pragma unroll
    for (int c = 0; c < 3; c++)
      vbold[i][c] = FIRST ? 0.f : vA[(nb + q*4 + i)*D3 + c*DD + dc];
  __syncthreads();
  // ---- capture v delta, add bases to VN chunks (regs) and XN (in place) ----
  float voldd[4][3];
  #pragma unroll
  for (int i = 0; i < 4; i++)
    #pragma unroll
    for (int c = 0; c < 3; c++) voldd[i][c] = VN(c*16 + q*4 + i, dc);
  float4 cf[3];
  {
    int ch = tid * 3;
    #pragma unroll
    for (int j = 0; j < 3; j++) {
      int r = (ch + j) >> 5, c4 = (ch + j) & 31;
      float4 t = *(const float4*)&VN(r, c4*4);
      cf[j] = make_float4(vb4[j].x + t.x, vb4[j].y + t.y, vb4[j].z + t.z, vb4[j].w + t.w);
    }
    int r = tid >> 5, c4 = tid & 31;
    float4 t = *(float4*)&XN(r, c4*4);
    *(float4*)&XN(r, c4*4) = make_float4(xb4.x + t.x, xb4.y + t.y, xb4.z + t.z, xb4.w + t.w);
  }
  __syncthreads();                      // all fp32 reads done before short overwrite
  {
    int ch = tid * 3;
    #pragma unroll
    for (int j = 0; j < 3; j++) {
      int r = (ch + j) >> 5, c4 = (ch + j) & 31;
      split_store4(cf[j], &VNH(r, c4*4), &VNL(r, c4*4));
    }
  }
  __syncthreads();
  // ---- phase 1: U & V projections for column-slice dc (A-fragments pre-split) ----
  v4f aU[3] = {}, aV[3] = {};
  #pragma unroll
  for (int s = 0; s < 4; s++) {
    long boff = (long)dc*128 + s*32 + q*8;
    v8s buh = *(const v8s*)(Uth + boff);
    v8s bul = *(const v8s*)(Utl + boff);
    v8s bvh = *(const v8s*)(Vth + boff);
    v8s bvl = *(const v8s*)(Vtl + boff);
    #pragma unroll
    for (int c = 0; c < 3; c++) {
      v8s ah = *(const v8s*)&VNH(c*16 + l15, s*32 + q*8);
      v8s al = *(const v8s*)&VNL(c*16 + l15, s*32 + q*8);
      MFMA3(aU[c], ah, al, buh, bul);
      MFMA3(aV[c], ah, al, bvh, bvl);
    }
  }
  float sreg[4], vn2[4];
  #pragma unroll
  for (int i = 0; i < 4; i++) {
    sreg[i] = aU[0][i]*aV[0][i] + aU[1][i]*aV[1][i] + aU[2][i]*aV[2][i];
    vn2[i]  = aV[0][i]*aV[0][i] + aV[1][i]*aV[1][i] + aV[2][i]*aV[2][i];
  }
  __syncthreads();   // all reads of VNH/VNL complete before CAT overlay
  // ---- build cat = [x_new | Vn] directly as bf16 hi/lo (split once by producer) ----
  {
    int r = tid >> 5, c4 = tid & 31;   // 512 tasks: 16 rows x 32 float4-chunks
    float4 f = *(const float4*)&XN(r, c4*4);
    split_store4(f, &CATH(r, c4*4), &CATL(r, c4*4));
  }
  #pragma unroll
  for (int i = 0; i < 4; i++) {
    short h, l;
    split2(sqrtf(vn2[i] + 1e-8f), h, l);
    CATH(q*4 + i, 128 + dc) = h;
    CATL(q*4 + i, 128 + dc) = l;
  }
  __syncthreads();
  // ---- GEMM1: t2[:, dc] = silu(cat @ Wu1 + b1), K=256; t2 written pre-split ----
  {
    v4f acc = {};
    #pragma unroll
    for (int s = 0; s < 8; s++) {
      v8s ah = *(const v8s*)&CATH(l15, s*32 + q*8);
      v8s al = *(const v8s*)&CATL(l15, s*32 + q*8);
      v8s bh = *(const v8s*)(W1h + (long)dc*256 + s*32 + q*8);
      v8s bl = *(const v8s*)(W1l + (long)dc*256 + s*32 + q*8);
      MFMA3(acc, ah, al, bh, bl);
    }
    float bb = b1[dc];
    #pragma unroll
    for (int i = 0; i < 4; i++) {
      short h, l;
      split2(silu_f(acc[i] + bb), h, l);
      T2H(q*4 + i, dc) = h;
      T2L(q*4 + i, dc) = l;
    }
  }
  __syncthreads();
  // ---- GEMM2 + epilogue ----
  {
    v4f acc[3] = {};
    #pragma unroll
    for (int s = 0; s < 4; s++) {
      v8s ah = *(const v8s*)&T2H(l15, s*32 + q*8);
      v8s al = *(const v8s*)&T2L(l15, s*32 + q*8);
      #pragma unroll
      for (int g = 0; g < 3; g++) {
        int n = g*128 + dc;                 // avv: dc, asv: 128+dc, ass: 256+dc
        v8s bh = *(const v8s*)(W2h + (long)n*128 + s*32 + q*8);
        v8s bl = *(const v8s*)(W2l + (long)n*128 + s*32 + q*8);
        MFMA3(acc[g], ah, al, bh, bl);
      }
    }
    float bavv = b2[dc], basv = b2[128 + dc], bass = b2[256 + dc];
    #pragma unroll
    for (int i = 0; i < 4; i++) {
      int lr = q*4 + i;
      long row = nb + lr;
      float avv = acc[0][i] + bavv;
      float asv = acc[1][i] + basv;
      float ass = acc[2][i] + bass;
      float xf = XN(lr, dc) + ass + asv * sreg[i];
      if (!LAST) {
        x[row*DD + dc] = xf;
        #pragma unroll
        for (int c = 0; c < 3; c++)
          vB[row*D3 + c*DD + dc] = fmaf(avv, aU[c][i], voldd[i][c] + vbold[i][c]);
      } else {
        XN(lr, dc) = xf;    // keep final x row in LDS for the fused head
      }
    }
  }
  // ---- fused output head (LAST only): out += silu(x@Wo1+bo1)@Wo2 + bo2 via MFMA ----
  if (LAST) {
    __syncthreads();        // all final XN writes visible
    // split final x rows to bf16 hi/lo: XH2 @sms 0, XL2 @sms 2176 (regions dead)
    {
      int r = tid >> 5, c4 = tid & 31;
      float4 f = *(const float4*)&XN(r, c4*4);
      split_store4(f, &sms[r*136 + c4*4], &sms[2176 + r*136 + c4*4]);
    }
    __syncthreads();
    // z[16][64] = x @ Wo1: waves 0-3 each own n-tile wv (h = wv*16 + l15)
    if (wv < 4) {
      int n = wv*16 + l15;
      v4f accz = {};
      #pragma unroll
      for (int s = 0; s < 4; s++) {
        v8s ah = *(const v8s*)&sms[l15*136 + s*32 + q*8];
        v8s al = *(const v8s*)&sms[2176 + l15*136 + s*32 + q*8];
        v8s bh = *(const v8s*)(WOh + (long)n*128 + s*32 + q*8);
        v8s bl = *(const v8s*)(WOl + (long)n*128 + s*32 + q*8);
        MFMA3(accz, ah, al, bh, bl);
      }
      float bo1v = bo1[n], wo2v = Wo2[n];
      #pragma unroll
      for (int i = 0; i < 4; i++) {
        float val = silu_f(accz[i] + bo1v) * wo2v;   // z[q*4+i][n]
        #pragma unroll
        for (int off = 1; off < 16; off <<= 1) val += __shfl_xor(val, off, 16);
        if (l15 == 0) smem[2200 + wv*16 + q*4 + i] = val;   // partial per (tile, row)
      }
    }
    __syncthreads();
    if (tid < 16) {
      float s_ = smem[2200 + tid] + smem[2200 + 16 + tid]
               + smem[2200 + 32 + tid] + smem[2200 + 48 + tid];
      atomicAdd(&out[batch[nb + tid]], s_ + bo2[0]);
    }
  }
  #undef VN
  #undef XN
  #undef VNH
  #undef VNL
  #undef CATH
  #undef CATL
  #undef T2H
  #undef T2L
}

// ---------------- launcher ----------------
extern "C" void kernel_launch(void* const* d_in, const int* in_sizes, int n_in,
                              void* d_out, int out_size, void* d_ws, size_t ws_size,
                              hipStream_t stream) {
  const int*   at_no = (const int*)d_in[0];
  const float* pos   = (const float*)d_in[1];
  const int*   ei    = (const int*)d_in[2];
  const int*   batch = (const int*)d_in[3];
  const float* emb   = (const float*)d_in[4];
  const float* Wf    = (const float*)d_in[5];
  const float* bfp   = (const float*)d_in[6];
  const float* Wm1   = (const float*)d_in[7];
  const float* bm1   = (const float*)d_in[8];
  const float* Wm2   = (const float*)d_in[9];
  const float* bm2   = (const float*)d_in[10];
  const float* U     = (const float*)d_in[11];
  const float* V     = (const float*)d_in[12];
  const float* Wu1   = (const float*)d_in[13];
  const float* bu1   = (const float*)d_in[14];
  const float* Wu2   = (const float*)d_in[15];
  const float* bu2   = (const float*)d_in[16];
  const float* Wo1   = (const float*)d_in[17];
  const float* bo1   = (const float*)d_in[18];
  const float* Wo2   = (const float*)d_in[19];
  const float* bo2   = (const float*)d_in[20];
  float* out = (float*)d_out;

  char* w = (char*)d_ws;
  auto alloc = [&](size_t bytes) -> void* {
    void* p = (void*)w;
    w += (bytes + 255) & ~(size_t)255;
    return p;
  };
  float*  x      = (float*)alloc(sizeof(float)*(size_t)NN*DD);
  float*  v_a    = (float*)alloc(sizeof(float)*(size_t)NN*D3);   // interleaved [NN][3][DD]
  float*  v_b    = (float*)alloc(sizeof(float)*(size_t)NN*D3);
  float*  phi    = (float*)alloc(sizeof(float)*(size_t)NN*D3);   // interleaved [NN][3][DD]
  short*  wbh    = (short*)alloc(sizeof(short)*(size_t)3*LSZ);   // bf16-hi weights
  short*  wbl    = (short*)alloc(sizeof(short)*(size_t)3*LSZ);   // bf16-lo weights
  short*  woh    = (short*)alloc(sizeof(short)*(size_t)HH*DD);   // Wo1 bf16-hi [64][128]
  short*  wol    = (short*)alloc(sizeof(short)*(size_t)HH*DD);   // Wo1 bf16-lo
  int*    srcs   = (int*)alloc(sizeof(int)*(size_t)ECAP);
  float4* eg1    = (float4*)alloc(sizeof(float4)*(size_t)ECAP);
  float4* eg2    = (float4*)alloc(sizeof(float4)*(size_t)ECAP);
  int*    indptr = (int*)alloc(sizeof(int)*((size_t)NN+1));
  int*    counts = (int*)alloc(sizeof(int)*(size_t)NN);

  if ((size_t)(w - (char*)d_ws) > ws_size) {   // diagnostic guard: zeros => ws too small
    zero_f_kernel<<<2, 256, 0, stream>>>(out, NG_);
    return;
  }

  // NOTE: v_a zero-fill not needed — layer 0 runs FIRST=1 and never reads vA.
  zero_f_kernel<<<2, 256, 0, stream>>>(out, NG_);
  zero_i_kernel<<<64, 256, 0, stream>>>(counts, NN);
  init_x_kernel<<<(NN*DD + 255)/256, 256, 0, stream>>>(at_no, emb, x);
  prep_w_kernel<<<(3*LSZ + 255)/256, 256, 0, stream>>>(Wm1, Wm2, U, V, Wu1, Wu2, wbh, wbl);
  prep_wo_kernel<<<(HH*DD + 255)/256, 256, 0, stream>>>(Wo1, woh, wol);
  hist_kernel<<<(NE + 255)/256, 256, 0, stream>>>(ei, pos, counts);
  scan_kernel<<<1, 1024, 0, stream>>>(counts, indptr, NN);
  zero_i_kernel<<<64, 256, 0, stream>>>(counts, NN);
  fill_kernel<<<(NE + 255)/256, 256, 0, stream>>>(ei, pos, indptr, counts, srcs, eg1, eg2);

  const int MB = (NN + 31) / 32;    // 1563
  float* vcur = v_a;
  float* vnext = v_b;
  for (int l = 0; l < 3; l++) {
    const float* Wf_l  = Wf  + (size_t)l*NB_*D3;
    const float* bf_l  = bfp + (size_t)l*D3;
    const float* bm1_l = bm1 + (size_t)l*DD;
    const float* bm2_l = bm2 + (size_t)l*D3;
    const float* bu1_l = bu1 + (size_t)l*DD;
    const float* bu2_l = bu2 + (size_t)l*D3;
    const short* Lh = wbh + (size_t)l*LSZ;
    const short* Ll = wbl + (size_t)l*LSZ;
    const short* Wm1h = Lh,          *Wm1L = Ll;
    const short* Wm2h = Lh + 16384,  *Wm2L = Ll + 16384;
    const short* Uh   = Lh + 65536,  *UL   = Ll + 65536;
    const short* Vh   = Lh + 81920,  *VL   = Ll + 81920;
    const short* Wu1h = Lh + 98304,  *Wu1L = Ll + 98304;
    const short* Wu2h = Lh + 131072, *Wu2L = Ll + 131072;

    // fused node-MLP: x -> t2 (LDS) -> phi interleaved [NN][3][DD]
    mlp_phi_kernel<<<MB, 512, 0, stream>>>(x, Wm1h, Wm1L, bm1_l, Wm2h, Wm2L, bm2_l,
                                           phi, NN);
    // fused: edge sweep + U/V proj + a-MLP + x,v update; templated per layer
    if (l == 0) {
      muva_kernel<1,0><<<NN/16, 512, 0, stream>>>(phi, vcur, vnext, x,
                                                  srcs, eg1, eg2, indptr, Wf_l, bf_l,
                                                  Uh, UL, Vh, VL,
                                                  Wu1h, Wu1L, bu1_l, Wu2h, Wu2L, bu2_l,
                                                  woh, wol, bo1, Wo2, bo2, batch, out);
    } else if (l == 1) {
      muva_kernel<0,0><<<NN/16, 512, 0, stream>>>(phi, vcur, vnext, x,
                                                  srcs, eg1, eg2, indptr, Wf_l, bf_l,
                                                  Uh, UL, Vh, VL,
                                                  Wu1h, Wu1L, bu1_l, Wu2h, Wu2L, bu2_l,
                                                  woh, wol, bo1, Wo2, bo2, batch, out);
    } else {
      muva_kernel<0,1><<<NN/16, 512, 0, stream>>>(phi, vcur, vnext, x,
                                                  srcs, eg1, eg2, indptr, Wf_l, bf_l,
                                                  Uh, UL, Vh, VL,
                                                  Wu1h, Wu1L, bu1_l, Wu2h, Wu2L, bu2_l,
                                                  woh, wol, bo1, Wo2, bo2, batch, out);
    }

    float* tmp = vcur; vcur = vnext; vnext = tmp;
  }

  (void)in_sizes; (void)n_in; (void)out_size; (void)ws_size;
}